// Round 1
// baseline (1004.736 us; speedup 1.0000x reference)
//
#include <hip/hip_runtime.h>
#include <hip/hip_bf16.h>
#include <cstdint>
#include <cstddef>

// ---------------- types ----------------
typedef __attribute__((ext_vector_type(8))) short bf16x8;
typedef __attribute__((ext_vector_type(4))) float f32x4;

#define HDIM 1024
#define IDIM 2048
#define TTOK 4096
#define NEXP 8
#define SHARED_BASE 8192        // routed slots 0..8191, shared rows 8192..12287
#define ROWS_TOTAL 12288
#define EXP_W_ELEMS 2097152ull  // 2048*1024 per weight matrix per expert

// ---------------- workspace layout (bytes) ----------------
#define OFF_WG   0ull
#define OFF_WU   (OFF_WG + 9ull * EXP_W_ELEMS * 2ull)
#define OFF_WD   (OFF_WU + 9ull * EXP_W_ELEMS * 2ull)
#define OFF_HF   (OFF_WD + 9ull * EXP_W_ELEMS * 2ull)            // [4096][1024] bf16
#define OFF_P    (OFF_HF + 4096ull * 1024ull * 2ull)             // [12288][2048] bf16
#define OFF_SLOT (OFF_P  + 12288ull * 2048ull * 2ull)            // [12288][1024] f32
#define OFF_TOPI (OFF_SLOT + 12288ull * 1024ull * 4ull)          // [8192] int
#define OFF_TOPW (OFF_TOPI + 8192ull * 4ull)                     // [8192] f32
#define OFF_PROB (OFF_TOPW + 8192ull * 4ull)                     // [4096][8] f32
#define OFF_ZENT (OFF_PROB + 4096ull * 8ull * 4ull)              // [4096][2] f32
#define OFF_META (OFF_ZENT + 4096ull * 2ull * 4ull)              // 48 ints (cnt/base/cursor)
#define OFF_LTOK (OFF_META + 256ull)                             // [12288] int
#define OFF_LW   (OFF_LTOK + 12288ull * 4ull)                    // [12288] f32
#define OFF_ROWS (OFF_LW + 12288ull * 4ull)                      // [8192] int

__device__ __forceinline__ float clamp500(float v) {
  return fminf(fmaxf(v, -500.f), 500.f);
}

__device__ __forceinline__ unsigned short f2bf(float f) {
  unsigned int u = __float_as_uint(f);
  u += 0x7FFFu + ((u >> 16) & 1u);  // RNE; inputs always finite here
  return (unsigned short)(u >> 16);
}

// async global->LDS, 16B per lane. LDS dest must be wave-uniform base + lane*16.
__device__ __forceinline__ void ld_g2l_16(const void* g, void* l) {
  __builtin_amdgcn_global_load_lds(
      (const __attribute__((address_space(1))) void*)g,
      (__attribute__((address_space(3))) void*)l, 16, 0, 0);
}

__device__ __forceinline__ f32x4 mfma16(bf16x8 a, bf16x8 b, f32x4 c) {
  return __builtin_amdgcn_mfma_f32_16x16x32_bf16(a, b, c, 0, 0, 0);
}

// ---------------- fp32 -> bf16 weight conversion ----------------
__global__ __launch_bounds__(256) void cvt_kernel(const float* __restrict__ src,
                                                  unsigned short* __restrict__ dst,
                                                  int n4) {
  int i = blockIdx.x * 256 + threadIdx.x;
  int stride = gridDim.x * 256;
  for (; i < n4; i += stride) {
    float4 f = ((const float4*)src)[i];
    uint2 pk;
    pk.x = (unsigned)f2bf(f.x) | ((unsigned)f2bf(f.y) << 16);
    pk.y = (unsigned)f2bf(f.z) | ((unsigned)f2bf(f.w) << 16);
    ((uint2*)dst)[i] = pk;
  }
}

// ---------------- router: LN -> logits -> softmax -> top2 + aux terms ----------------
__global__ __launch_bounds__(256) void router_kernel(
    const float* __restrict__ x, const float* __restrict__ lnw,
    const float* __restrict__ lnb, const float* __restrict__ rw,
    unsigned short* __restrict__ hf, int* __restrict__ top_i,
    float* __restrict__ top_w, float* __restrict__ probs_tok,
    float* __restrict__ zent) {
  int wv = threadIdx.x >> 6, lane = threadIdx.x & 63;
  int t = blockIdx.x * 4 + wv;  // one wave per token
  const float* xr = x + (size_t)t * HDIM;
  float v[16];
  float s = 0.f;
#pragma unroll
  for (int j = 0; j < 16; ++j) {
    int h = j * 64 + lane;
    float f = clamp500(xr[h]);
    v[j] = f;
    hf[(size_t)t * HDIM + h] = f2bf(f);
    s += f;
  }
#pragma unroll
  for (int m = 32; m; m >>= 1) s += __shfl_xor(s, m);
  float mu = s * (1.f / HDIM);
  float s2 = 0.f;
#pragma unroll
  for (int j = 0; j < 16; ++j) { float d = v[j] - mu; s2 += d * d; }
#pragma unroll
  for (int m = 32; m; m >>= 1) s2 += __shfl_xor(s2, m);
  float rstd = rsqrtf(s2 * (1.f / HDIM) + 1e-5f);
  float acc[8];
#pragma unroll
  for (int e = 0; e < 8; ++e) acc[e] = 0.f;
#pragma unroll
  for (int j = 0; j < 16; ++j) {
    int h = j * 64 + lane;
    float hn = (v[j] - mu) * rstd * lnw[h] + lnb[h];
    hn = fminf(fmaxf(hn, -50.f), 50.f);
#pragma unroll
    for (int e = 0; e < 8; ++e) acc[e] += hn * rw[e * HDIM + h];
  }
#pragma unroll
  for (int e = 0; e < 8; ++e) {
    float a = acc[e];
#pragma unroll
    for (int m = 32; m; m >>= 1) a += __shfl_xor(a, m);
    acc[e] = a;
  }
  if (lane == 0) {
    float lg[8], mx = -1e30f;
#pragma unroll
    for (int e = 0; e < 8; ++e) {
      float l = fminf(fmaxf(acc[e], -10.f), 10.f);
      lg[e] = l;
      mx = fmaxf(mx, l);
    }
    float se = 0.f;
    float ex[8];
#pragma unroll
    for (int e = 0; e < 8; ++e) { ex[e] = expf(lg[e] - mx); se += ex[e]; }
    float inv = 1.f / se;
    float pr[8];
#pragma unroll
    for (int e = 0; e < 8; ++e) {
      float p = ex[e] * inv;
      pr[e] = fminf(fmaxf(p, 1e-4f), 1.f);
      probs_tok[t * 8 + e] = pr[e];
    }
    int i0 = 0; float v0 = pr[0];
#pragma unroll
    for (int e = 1; e < 8; ++e) if (pr[e] > v0) { v0 = pr[e]; i0 = e; }
    int i1 = -1; float v1 = -1.f;
#pragma unroll
    for (int e = 0; e < 8; ++e) if (e != i0 && pr[e] > v1) { v1 = pr[e]; i1 = e; }
    float dsum = fmaxf(v0 + v1, 1e-4f);
    top_i[2 * t] = i0; top_i[2 * t + 1] = i1;
    top_w[2 * t] = v0 / dsum; top_w[2 * t + 1] = v1 / dsum;
    float lse = mx + logf(se);
    zent[2 * t] = lse * lse;
    float ent = 0.f;
#pragma unroll
    for (int e = 0; e < 8; ++e) {
      float ps = fminf(fmaxf(pr[e], 1e-4f), 1.f - 1e-4f);
      ent -= ps * logf(ps);
    }
    zent[2 * t + 1] = ent;
  }
}

// ---------------- aux loss + expert offsets (single block, deterministic) ----------------
__global__ __launch_bounds__(256) void aux_kernel(
    const int* __restrict__ top_i, const float* __restrict__ probs_tok,
    const float* __restrict__ zent, int* __restrict__ meta,
    float* __restrict__ aux_out) {
  __shared__ int sc[8];
  __shared__ float red[256];
  __shared__ float sums[10];
  int tid = threadIdx.x;
  if (tid < 8) sc[tid] = 0;
  __syncthreads();
  for (int s = tid; s < 8192; s += 256) atomicAdd(&sc[top_i[s]], 1);
  float pe[8] = {0, 0, 0, 0, 0, 0, 0, 0};
  float zs = 0.f, es = 0.f;
  for (int t = tid; t < 4096; t += 256) {
#pragma unroll
    for (int e = 0; e < 8; ++e) pe[e] += probs_tok[t * 8 + e];
    zs += zent[2 * t];
    es += zent[2 * t + 1];
  }
  for (int e = 0; e < 10; ++e) {
    float val = (e < 8) ? pe[e] : ((e == 8) ? zs : es);
    red[tid] = val;
    __syncthreads();
    for (int off = 128; off; off >>= 1) {
      if (tid < off) red[tid] += red[tid + off];
      __syncthreads();
    }
    if (tid == 0) sums[e] = red[0];
    __syncthreads();
  }
  if (tid == 0) {
    float lb = 0.f, usage = 0.f;
    for (int e = 0; e < 8; ++e) {
      float tpe = (float)sc[e] / 8192.f;
      float avg = sums[e] / 4096.f;
      lb += tpe * avg;
      usage += (tpe > 0.01f) ? 1.f : 0.f;
    }
    lb *= 8.f;
    float z_loss = (sums[8] / 4096.f) * 0.001f;
    float ent_loss = fmaxf(logf(8.f) - sums[9] / 4096.f, 0.f) * 0.01f;
    float util = (1.f - usage / 8.f) * 0.1f;
    float aux = fminf(fmaxf(lb + z_loss + ent_loss + util, 0.f), 10.f);
    *aux_out = aux;
    int base = 0;
    for (int e = 0; e < 8; ++e) {
      meta[e] = sc[e];
      meta[16 + e] = base;
      base += sc[e];
      meta[32 + e] = 0;
    }
    meta[8] = TTOK;            // shared "expert"
    meta[16 + 8] = SHARED_BASE;
    meta[32 + 8] = 0;
  }
}

// ---------------- scatter tokens into per-expert lists ----------------
__global__ __launch_bounds__(256) void scatter_kernel(
    const int* __restrict__ top_i, const float* __restrict__ top_w,
    int* __restrict__ meta, int* __restrict__ ltok, float* __restrict__ lw,
    int* __restrict__ rowslot) {
  int s = blockIdx.x * 256 + threadIdx.x;
  if (s < 8192) {
    int e = top_i[s];
    int pos = atomicAdd(&meta[32 + e], 1);
    int idx = meta[16 + e] + pos;
    ltok[idx] = s >> 1;
    lw[idx] = top_w[s];
    rowslot[s] = idx;
  }
  if (s < TTOK) {  // identity list for shared expert
    ltok[SHARED_BASE + s] = s;
    lw[SHARED_BASE + s] = 1.f;
  }
}

// ---------------- GEMM1: P = clamp(silu(clamp(A*Wg^T)) * clamp(A*Wu^T)) ----------------
// tile 128x128, BK=64, 4 waves (2x2), 16x16x32 bf16 MFMA
__global__ __launch_bounds__(256) void gemm1_kernel(
    const unsigned short* __restrict__ hf,
    const unsigned short* __restrict__ wg_all,
    const unsigned short* __restrict__ wu_all,
    unsigned short* __restrict__ P,
    const int* __restrict__ meta, const int* __restrict__ ltok) {
  int mt = blockIdx.x, nt = blockIdx.y, ex = blockIdx.z;
  int cnt = meta[ex];
  if (mt * 128 >= cnt) return;
  int base = meta[16 + ex];
  __shared__ unsigned short sA[128 * 64], sG[128 * 64], sU[128 * 64];
  int tid = threadIdx.x, lane = tid & 63, wv = tid >> 6;
  int wr = wv >> 1, wc = wv & 1;
  int ar = tid >> 3;        // staging row within 32-row chunk
  int ac = (tid & 7) * 8;   // staging col (bf16 elements)
  int tok[4];
#pragma unroll
  for (int c = 0; c < 4; ++c) {
    int r = mt * 128 + c * 32 + ar;
    tok[c] = (r < cnt) ? ltok[base + r] : 0;
  }
  const unsigned short* wg = wg_all + (size_t)ex * EXP_W_ELEMS;
  const unsigned short* wu = wu_all + (size_t)ex * EXP_W_ELEMS;
  int n0 = nt * 128;
  f32x4 zero = {0.f, 0.f, 0.f, 0.f};
  f32x4 accg[4][4], accu[4][4];
#pragma unroll
  for (int m = 0; m < 4; ++m)
#pragma unroll
    for (int n = 0; n < 4; ++n) { accg[m][n] = zero; accu[m][n] = zero; }

  for (int k0 = 0; k0 < HDIM; k0 += 64) {
    __syncthreads();
#pragma unroll
    for (int c = 0; c < 4; ++c) {
      int lr = c * 32 + ar;
      ld_g2l_16(hf + (size_t)tok[c] * HDIM + k0 + ac, &sA[lr * 64 + ac]);
      ld_g2l_16(wg + (size_t)(n0 + lr) * HDIM + k0 + ac, &sG[lr * 64 + ac]);
      ld_g2l_16(wu + (size_t)(n0 + lr) * HDIM + k0 + ac, &sU[lr * 64 + ac]);
    }
    __syncthreads();
#pragma unroll
    for (int kk = 0; kk < 2; ++kk) {
      int ko = kk * 32 + (lane >> 4) * 8;
      bf16x8 af[4], gf[4], uf[4];
#pragma unroll
      for (int m = 0; m < 4; ++m)
        af[m] = *(const bf16x8*)&sA[(wr * 64 + m * 16 + (lane & 15)) * 64 + ko];
#pragma unroll
      for (int n = 0; n < 4; ++n) {
        gf[n] = *(const bf16x8*)&sG[(wc * 64 + n * 16 + (lane & 15)) * 64 + ko];
        uf[n] = *(const bf16x8*)&sU[(wc * 64 + n * 16 + (lane & 15)) * 64 + ko];
      }
#pragma unroll
      for (int m = 0; m < 4; ++m)
#pragma unroll
        for (int n = 0; n < 4; ++n) {
          accg[m][n] = mfma16(af[m], gf[n], accg[m][n]);
          accu[m][n] = mfma16(af[m], uf[n], accu[m][n]);
        }
    }
  }
  // epilogue: SwiGLU, write bf16 P.  C/D layout: col=lane&15, row=(lane>>4)*4+reg
  int rbase = mt * 128 + wr * 64 + (lane >> 4) * 4;
  int cbase = n0 + wc * 64 + (lane & 15);
#pragma unroll
  for (int m = 0; m < 4; ++m) {
#pragma unroll
    for (int r = 0; r < 4; ++r) {
      int row = rbase + m * 16 + r;
      if (row < cnt) {
        size_t prow = (size_t)(base + row) * IDIM;
#pragma unroll
        for (int n = 0; n < 4; ++n) {
          float g = clamp500(accg[m][n][r]);
          float u = clamp500(accu[m][n][r]);
          float sl = g / (1.f + __expf(-g));
          float p = clamp500(sl * u);
          P[prow + cbase + n * 16] = f2bf(p);
        }
      }
    }
  }
}

// ---------------- GEMM2: slot = weight * clamp(P*Wd^T)  (shared: clamp(clamp(.)*sig)) ----------------
__global__ __launch_bounds__(256) void gemm2_kernel(
    const unsigned short* __restrict__ P,
    const unsigned short* __restrict__ wd_all,
    float* __restrict__ slot,
    const int* __restrict__ meta, const float* __restrict__ lw,
    const float* __restrict__ sgate) {
  int mt = blockIdx.x, nt = blockIdx.y, ex = blockIdx.z;
  int cnt = meta[ex];
  if (mt * 128 >= cnt) return;
  int base = meta[16 + ex];
  __shared__ unsigned short sA[128 * 64], sB[128 * 64];
  int tid = threadIdx.x, lane = tid & 63, wv = tid >> 6;
  int wr = wv >> 1, wc = wv & 1;
  int ar = tid >> 3;
  int ac = (tid & 7) * 8;
  const unsigned short* wd = wd_all + (size_t)ex * EXP_W_ELEMS;
  int n0 = nt * 128;
  f32x4 zero = {0.f, 0.f, 0.f, 0.f};
  f32x4 acc[4][4];
#pragma unroll
  for (int m = 0; m < 4; ++m)
#pragma unroll
    for (int n = 0; n < 4; ++n) acc[m][n] = zero;

  for (int k0 = 0; k0 < IDIM; k0 += 64) {
    __syncthreads();
#pragma unroll
    for (int c = 0; c < 4; ++c) {
      int lr = c * 32 + ar;
      ld_g2l_16(P + (size_t)(base + mt * 128 + lr) * IDIM + k0 + ac, &sA[lr * 64 + ac]);
      ld_g2l_16(wd + (size_t)(n0 + lr) * IDIM + k0 + ac, &sB[lr * 64 + ac]);
    }
    __syncthreads();
#pragma unroll
    for (int kk = 0; kk < 2; ++kk) {
      int ko = kk * 32 + (lane >> 4) * 8;
      bf16x8 af[4], bfr[4];
#pragma unroll
      for (int m = 0; m < 4; ++m)
        af[m] = *(const bf16x8*)&sA[(wr * 64 + m * 16 + (lane & 15)) * 64 + ko];
#pragma unroll
      for (int n = 0; n < 4; ++n)
        bfr[n] = *(const bf16x8*)&sB[(wc * 64 + n * 16 + (lane & 15)) * 64 + ko];
#pragma unroll
      for (int m = 0; m < 4; ++m)
#pragma unroll
        for (int n = 0; n < 4; ++n)
          acc[m][n] = mfma16(af[m], bfr[n], acc[m][n]);
    }
  }
  float gsig = 1.f / (1.f + __expf(-sgate[0]));
  int rbase = mt * 128 + wr * 64 + (lane >> 4) * 4;
  int cbase = n0 + wc * 64 + (lane & 15);
#pragma unroll
  for (int m = 0; m < 4; ++m) {
#pragma unroll
    for (int r = 0; r < 4; ++r) {
      int row = rbase + m * 16 + r;
      if (row < cnt) {
        float wgt = (ex == 8) ? 1.f : lw[base + row];
        size_t srow = (size_t)(base + row) * HDIM;
#pragma unroll
        for (int n = 0; n < 4; ++n) {
          float o = clamp500(acc[m][n][r]);
          float val = (ex == 8) ? clamp500(o * gsig) : wgt * o;
          slot[srow + cbase + n * 16] = val;
        }
      }
    }
  }
}

// ---------------- combine: final = clamp(slot0 + slot1 + shared) ----------------
__global__ __launch_bounds__(256) void combine_kernel(
    const float* __restrict__ slot, const int* __restrict__ rowslot,
    float* __restrict__ out) {
  int i = blockIdx.x * 256 + threadIdx.x;  // float4 index; 1 block == 1 token row
  int t = i >> 8;
  int c = (i & 255) * 4;
  int r0 = rowslot[2 * t], r1 = rowslot[2 * t + 1];
  float4 va = *(const float4*)(slot + (size_t)r0 * HDIM + c);
  float4 vb = *(const float4*)(slot + (size_t)r1 * HDIM + c);
  float4 vs = *(const float4*)(slot + (size_t)(SHARED_BASE + t) * HDIM + c);
  float4 o;
  o.x = clamp500(va.x + vb.x + vs.x);
  o.y = clamp500(va.y + vb.y + vs.y);
  o.z = clamp500(va.z + vb.z + vs.z);
  o.w = clamp500(va.w + vb.w + vs.w);
  *(float4*)(out + (size_t)t * HDIM + c) = o;
}

// ---------------- launch ----------------
extern "C" void kernel_launch(void* const* d_in, const int* in_sizes, int n_in,
                              void* d_out, int out_size, void* d_ws, size_t ws_size,
                              hipStream_t stream) {
  const float* x     = (const float*)d_in[0];
  const float* lnw   = (const float*)d_in[1];
  const float* lnb   = (const float*)d_in[2];
  const float* rw    = (const float*)d_in[3];
  const float* wg_f  = (const float*)d_in[4];
  const float* wu_f  = (const float*)d_in[5];
  const float* wd_f  = (const float*)d_in[6];
  const float* swg_f = (const float*)d_in[7];
  const float* swu_f = (const float*)d_in[8];
  const float* swd_f = (const float*)d_in[9];
  const float* sgate = (const float*)d_in[10];
  float* out = (float*)d_out;

  char* ws = (char*)d_ws;
  unsigned short* wgb = (unsigned short*)(ws + OFF_WG);
  unsigned short* wub = (unsigned short*)(ws + OFF_WU);
  unsigned short* wdb = (unsigned short*)(ws + OFF_WD);
  unsigned short* hf  = (unsigned short*)(ws + OFF_HF);
  unsigned short* P   = (unsigned short*)(ws + OFF_P);
  float* slot    = (float*)(ws + OFF_SLOT);
  int*   top_i   = (int*)(ws + OFF_TOPI);
  float* top_w   = (float*)(ws + OFF_TOPW);
  float* probs   = (float*)(ws + OFF_PROB);
  float* zent    = (float*)(ws + OFF_ZENT);
  int*   meta    = (int*)(ws + OFF_META);
  int*   ltok    = (int*)(ws + OFF_LTOK);
  float* lw      = (float*)(ws + OFF_LW);
  int*   rowslot = (int*)(ws + OFF_ROWS);

  // weights fp32 -> bf16 (experts 0..7 from dense arrays, shared as expert 8)
  cvt_kernel<<<2048, 256, 0, stream>>>(wg_f, wgb, (int)(8 * EXP_W_ELEMS / 4));
  cvt_kernel<<<2048, 256, 0, stream>>>(wu_f, wub, (int)(8 * EXP_W_ELEMS / 4));
  cvt_kernel<<<2048, 256, 0, stream>>>(wd_f, wdb, (int)(8 * EXP_W_ELEMS / 4));
  cvt_kernel<<<512, 256, 0, stream>>>(swg_f, wgb + 8 * EXP_W_ELEMS, (int)(EXP_W_ELEMS / 4));
  cvt_kernel<<<512, 256, 0, stream>>>(swu_f, wub + 8 * EXP_W_ELEMS, (int)(EXP_W_ELEMS / 4));
  cvt_kernel<<<512, 256, 0, stream>>>(swd_f, wdb + 8 * EXP_W_ELEMS, (int)(EXP_W_ELEMS / 4));

  router_kernel<<<TTOK / 4, 256, 0, stream>>>(x, lnw, lnb, rw, hf, top_i, top_w, probs, zent);
  aux_kernel<<<1, 256, 0, stream>>>(top_i, probs, zent, meta, out + (size_t)TTOK * HDIM);
  scatter_kernel<<<32, 256, 0, stream>>>(top_i, top_w, meta, ltok, lw, rowslot);

  gemm1_kernel<<<dim3(32, 16, 9), 256, 0, stream>>>(hf, wgb, wub, P, meta, ltok);
  gemm2_kernel<<<dim3(32, 8, 9), 256, 0, stream>>>(P, wdb, slot, meta, lw, sgate);
  combine_kernel<<<TTOK * HDIM / 4 / 256, 256, 0, stream>>>(slot, rowslot, out);
}

// Round 2
// 500.275 us; speedup vs baseline: 2.0084x; 2.0084x over previous
//
#include <hip/hip_runtime.h>
#include <hip/hip_bf16.h>
#include <cstdint>
#include <cstddef>

// ---------------- types ----------------
typedef __attribute__((ext_vector_type(8))) short bf16x8;
typedef __attribute__((ext_vector_type(4))) float f32x4;

#define HDIM 1024
#define IDIM 2048
#define TTOK 4096
#define NEXP 8
#define ROWS_PAD 13312          // padded routed (<=9088) + shared 4096, +slack
#define MT_MAX 104              // max m-tiles: <=71 routed + 32 shared
#define EXP_W_ELEMS 2097152ull  // 2048*1024 per weight matrix per expert

// ---------------- workspace layout (bytes) ----------------
#define OFF_WG   0ull
#define OFF_WU   (OFF_WG + 9ull * EXP_W_ELEMS * 2ull)
#define OFF_WD   (OFF_WU + 9ull * EXP_W_ELEMS * 2ull)
#define OFF_HF   (OFF_WD + 9ull * EXP_W_ELEMS * 2ull)            // [4096][1024] bf16
#define OFF_P    (OFF_HF + 4096ull * 1024ull * 2ull)             // [ROWS_PAD][2048] bf16
#define OFF_SLOT (OFF_P  + (size_t)ROWS_PAD * 2048ull * 2ull)    // [ROWS_PAD][1024] f32
#define OFF_TOPI (OFF_SLOT + (size_t)ROWS_PAD * 1024ull * 4ull)  // [8192] int
#define OFF_TOPW (OFF_TOPI + 8192ull * 4ull)                     // [8192] f32
#define OFF_PROB (OFF_TOPW + 8192ull * 4ull)                     // [4096][8] f32
#define OFF_ZENT (OFF_PROB + 4096ull * 8ull * 4ull)              // [4096][2] f32
#define OFF_META (OFF_ZENT + 4096ull * 2ull * 4ull)              // ints: cnt/base/cursor/tilecnt + tile map
#define OFF_LTOK (OFF_META + 4096ull)                            // [ROWS_PAD] int
#define OFF_LW   (OFF_LTOK + (size_t)ROWS_PAD * 4ull)            // [ROWS_PAD] f32
#define OFF_ROWS (OFF_LW + (size_t)ROWS_PAD * 4ull)              // [8192] int

// meta layout (ints): [0..8]=cnt, [16..24]=padded slot base, [32..40]=cursor,
//                     [48]=ntiles, [64..167]=tile->expert, [192..295]=tile->row0

__device__ __forceinline__ float clamp500(float v) {
  return fminf(fmaxf(v, -500.f), 500.f);
}

__device__ __forceinline__ unsigned short f2bf(float f) {
  unsigned int u = __float_as_uint(f);
  u += 0x7FFFu + ((u >> 16) & 1u);  // RNE; inputs always finite here
  return (unsigned short)(u >> 16);
}

// async global->LDS, 16B per lane. LDS dest must be wave-uniform base + lane*16.
__device__ __forceinline__ void ld_g2l_16(const void* g, void* l) {
  __builtin_amdgcn_global_load_lds(
      (const __attribute__((address_space(1))) void*)g,
      (__attribute__((address_space(3))) void*)l, 16, 0, 0);
}

__device__ __forceinline__ f32x4 mfma16(bf16x8 a, bf16x8 b, f32x4 c) {
  return __builtin_amdgcn_mfma_f32_16x16x32_bf16(a, b, c, 0, 0, 0);
}

// ---------------- fp32 -> bf16 weight conversion ----------------
__global__ __launch_bounds__(256) void cvt_kernel(const float* __restrict__ src,
                                                  unsigned short* __restrict__ dst,
                                                  int n4) {
  int i = blockIdx.x * 256 + threadIdx.x;
  int stride = gridDim.x * 256;
  for (; i < n4; i += stride) {
    float4 f = ((const float4*)src)[i];
    uint2 pk;
    pk.x = (unsigned)f2bf(f.x) | ((unsigned)f2bf(f.y) << 16);
    pk.y = (unsigned)f2bf(f.z) | ((unsigned)f2bf(f.w) << 16);
    ((uint2*)dst)[i] = pk;
  }
}

// ---------------- router: LN -> logits -> softmax -> top2 + aux terms ----------------
__global__ __launch_bounds__(256) void router_kernel(
    const float* __restrict__ x, const float* __restrict__ lnw,
    const float* __restrict__ lnb, const float* __restrict__ rw,
    unsigned short* __restrict__ hf, int* __restrict__ top_i,
    float* __restrict__ top_w, float* __restrict__ probs_tok,
    float* __restrict__ zent) {
  int wv = threadIdx.x >> 6, lane = threadIdx.x & 63;
  int t = blockIdx.x * 4 + wv;  // one wave per token
  const float* xr = x + (size_t)t * HDIM;
  float v[16];
  float s = 0.f;
#pragma unroll
  for (int j = 0; j < 16; ++j) {
    int h = j * 64 + lane;
    float f = clamp500(xr[h]);
    v[j] = f;
    hf[(size_t)t * HDIM + h] = f2bf(f);
    s += f;
  }
#pragma unroll
  for (int m = 32; m; m >>= 1) s += __shfl_xor(s, m);
  float mu = s * (1.f / HDIM);
  float s2 = 0.f;
#pragma unroll
  for (int j = 0; j < 16; ++j) { float d = v[j] - mu; s2 += d * d; }
#pragma unroll
  for (int m = 32; m; m >>= 1) s2 += __shfl_xor(s2, m);
  float rstd = rsqrtf(s2 * (1.f / HDIM) + 1e-5f);
  float acc[8];
#pragma unroll
  for (int e = 0; e < 8; ++e) acc[e] = 0.f;
#pragma unroll
  for (int j = 0; j < 16; ++j) {
    int h = j * 64 + lane;
    float hn = (v[j] - mu) * rstd * lnw[h] + lnb[h];
    hn = fminf(fmaxf(hn, -50.f), 50.f);
#pragma unroll
    for (int e = 0; e < 8; ++e) acc[e] += hn * rw[e * HDIM + h];
  }
#pragma unroll
  for (int e = 0; e < 8; ++e) {
    float a = acc[e];
#pragma unroll
    for (int m = 32; m; m >>= 1) a += __shfl_xor(a, m);
    acc[e] = a;
  }
  if (lane == 0) {
    float lg[8], mx = -1e30f;
#pragma unroll
    for (int e = 0; e < 8; ++e) {
      float l = fminf(fmaxf(acc[e], -10.f), 10.f);
      lg[e] = l;
      mx = fmaxf(mx, l);
    }
    float se = 0.f;
    float ex[8];
#pragma unroll
    for (int e = 0; e < 8; ++e) { ex[e] = expf(lg[e] - mx); se += ex[e]; }
    float inv = 1.f / se;
    float pr[8];
#pragma unroll
    for (int e = 0; e < 8; ++e) {
      float p = ex[e] * inv;
      pr[e] = fminf(fmaxf(p, 1e-4f), 1.f);
      probs_tok[t * 8 + e] = pr[e];
    }
    int i0 = 0; float v0 = pr[0];
#pragma unroll
    for (int e = 1; e < 8; ++e) if (pr[e] > v0) { v0 = pr[e]; i0 = e; }
    int i1 = -1; float v1 = -1.f;
#pragma unroll
    for (int e = 0; e < 8; ++e) if (e != i0 && pr[e] > v1) { v1 = pr[e]; i1 = e; }
    float dsum = fmaxf(v0 + v1, 1e-4f);
    top_i[2 * t] = i0; top_i[2 * t + 1] = i1;
    top_w[2 * t] = v0 / dsum; top_w[2 * t + 1] = v1 / dsum;
    float lse = mx + logf(se);
    zent[2 * t] = lse * lse;
    float ent = 0.f;
#pragma unroll
    for (int e = 0; e < 8; ++e) {
      float ps = fminf(fmaxf(pr[e], 1e-4f), 1.f - 1e-4f);
      ent -= ps * logf(ps);
    }
    zent[2 * t + 1] = ent;
  }
}

// ---------------- aux loss + padded tile map (single block, deterministic) ----------------
__global__ __launch_bounds__(256) void aux_kernel(
    const int* __restrict__ top_i, const float* __restrict__ probs_tok,
    const float* __restrict__ zent, int* __restrict__ meta,
    int* __restrict__ ltok, float* __restrict__ lw,
    float* __restrict__ aux_out) {
  __shared__ int sc[8];
  __shared__ float red[256];
  __shared__ float sums[10];
  int tid = threadIdx.x;
  if (tid < 8) sc[tid] = 0;
  __syncthreads();
  for (int s = tid; s < 8192; s += 256) atomicAdd(&sc[top_i[s]], 1);
  // default-init padded token lists (scatter overwrites the live ones)
  for (int i = tid; i < ROWS_PAD; i += 256) { ltok[i] = 0; lw[i] = 0.f; }
  float pe[8] = {0, 0, 0, 0, 0, 0, 0, 0};
  float zs = 0.f, es = 0.f;
  for (int t = tid; t < 4096; t += 256) {
#pragma unroll
    for (int e = 0; e < 8; ++e) pe[e] += probs_tok[t * 8 + e];
    zs += zent[2 * t];
    es += zent[2 * t + 1];
  }
  for (int e = 0; e < 10; ++e) {
    float val = (e < 8) ? pe[e] : ((e == 8) ? zs : es);
    red[tid] = val;
    __syncthreads();
    for (int off = 128; off; off >>= 1) {
      if (tid < off) red[tid] += red[tid + off];
      __syncthreads();
    }
    if (tid == 0) sums[e] = red[0];
    __syncthreads();
  }
  if (tid == 0) {
    float lb = 0.f, usage = 0.f;
    for (int e = 0; e < 8; ++e) {
      float tpe = (float)sc[e] / 8192.f;
      float avg = sums[e] / 4096.f;
      lb += tpe * avg;
      usage += (tpe > 0.01f) ? 1.f : 0.f;
    }
    lb *= 8.f;
    float z_loss = (sums[8] / 4096.f) * 0.001f;
    float ent_loss = fmaxf(logf(8.f) - sums[9] / 4096.f, 0.f) * 0.01f;
    float util = (1.f - usage / 8.f) * 0.1f;
    float aux = fminf(fmaxf(lb + z_loss + ent_loss + util, 0.f), 10.f);
    *aux_out = aux;
    // padded tile map
    int base = 0, tct = 0;
    for (int e = 0; e < 8; ++e) {
      int cnt = sc[e];
      meta[e] = cnt;
      meta[16 + e] = base;
      meta[32 + e] = 0;
      int nt = (cnt + 127) >> 7;
      for (int i = 0; i < nt; ++i) { meta[64 + tct] = e; meta[192 + tct] = base + i * 128; ++tct; }
      base += nt * 128;
    }
    meta[8] = TTOK;           // shared "expert"
    meta[16 + 8] = base;      // shared padded base
    meta[32 + 8] = 0;
    for (int i = 0; i < 32; ++i) { meta[64 + tct] = 8; meta[192 + tct] = base + i * 128; ++tct; }
    meta[48] = tct;
  }
}

// ---------------- scatter tokens into per-expert padded lists ----------------
__global__ __launch_bounds__(256) void scatter_kernel(
    const int* __restrict__ top_i, const float* __restrict__ top_w,
    int* __restrict__ meta, int* __restrict__ ltok, float* __restrict__ lw,
    int* __restrict__ rowslot) {
  int s = blockIdx.x * 256 + threadIdx.x;
  if (s < 8192) {
    int e = top_i[s];
    int pos = atomicAdd(&meta[32 + e], 1);
    int idx = meta[16 + e] + pos;
    ltok[idx] = s >> 1;
    lw[idx] = top_w[s];
    rowslot[s] = idx;
  }
  if (s < TTOK) {  // identity list for shared expert
    int sb = meta[16 + 8];
    ltok[sb + s] = s;
    lw[sb + s] = 1.f;
  }
}

// ---------------- GEMM1: P = clamp(silu(clamp(A*Wg^T)) * clamp(A*Wu^T)) ----------------
// tile 128x128, BK=64, 4 waves (2x2), 16x16x32 bf16 MFMA; mtile from padded map
__global__ __launch_bounds__(256) void gemm1_kernel(
    const unsigned short* __restrict__ hf,
    const unsigned short* __restrict__ wg_all,
    const unsigned short* __restrict__ wu_all,
    unsigned short* __restrict__ P,
    const int* __restrict__ meta, const int* __restrict__ ltok) {
  int mt = blockIdx.y, nt = blockIdx.x;
  if (mt >= meta[48]) return;
  int ex = meta[64 + mt];
  int r0 = meta[192 + mt];
  __shared__ unsigned short sA[128 * 64], sG[128 * 64], sU[128 * 64];
  int tid = threadIdx.x, lane = tid & 63, wv = tid >> 6;
  int wr = wv >> 1, wc = wv & 1;
  int ar = tid >> 3;        // staging row within 32-row chunk
  int ac = (tid & 7) * 8;   // staging col (bf16 elements)
  int tok[4];
#pragma unroll
  for (int c = 0; c < 4; ++c) tok[c] = ltok[r0 + c * 32 + ar];
  const unsigned short* wg = wg_all + (size_t)ex * EXP_W_ELEMS;
  const unsigned short* wu = wu_all + (size_t)ex * EXP_W_ELEMS;
  int n0 = nt * 128;
  f32x4 zero = {0.f, 0.f, 0.f, 0.f};
  f32x4 accg[4][4], accu[4][4];
#pragma unroll
  for (int m = 0; m < 4; ++m)
#pragma unroll
    for (int n = 0; n < 4; ++n) { accg[m][n] = zero; accu[m][n] = zero; }

  for (int k0 = 0; k0 < HDIM; k0 += 64) {
    __syncthreads();
#pragma unroll
    for (int c = 0; c < 4; ++c) {
      int lr = c * 32 + ar;
      ld_g2l_16(hf + (size_t)tok[c] * HDIM + k0 + ac, &sA[lr * 64 + ac]);
      ld_g2l_16(wg + (size_t)(n0 + lr) * HDIM + k0 + ac, &sG[lr * 64 + ac]);
      ld_g2l_16(wu + (size_t)(n0 + lr) * HDIM + k0 + ac, &sU[lr * 64 + ac]);
    }
    __syncthreads();
#pragma unroll
    for (int kk = 0; kk < 2; ++kk) {
      int ko = kk * 32 + (lane >> 4) * 8;
      bf16x8 af[4], gf[4], uf[4];
#pragma unroll
      for (int m = 0; m < 4; ++m)
        af[m] = *(const bf16x8*)&sA[(wr * 64 + m * 16 + (lane & 15)) * 64 + ko];
#pragma unroll
      for (int n = 0; n < 4; ++n) {
        gf[n] = *(const bf16x8*)&sG[(wc * 64 + n * 16 + (lane & 15)) * 64 + ko];
        uf[n] = *(const bf16x8*)&sU[(wc * 64 + n * 16 + (lane & 15)) * 64 + ko];
      }
#pragma unroll
      for (int m = 0; m < 4; ++m)
#pragma unroll
        for (int n = 0; n < 4; ++n) {
          accg[m][n] = mfma16(af[m], gf[n], accg[m][n]);
          accu[m][n] = mfma16(af[m], uf[n], accu[m][n]);
        }
    }
  }
  // epilogue: SwiGLU, write bf16 P (padded rows are junk, never read)
  int rbase = r0 + wr * 64 + (lane >> 4) * 4;
  int cbase = n0 + wc * 64 + (lane & 15);
#pragma unroll
  for (int m = 0; m < 4; ++m) {
#pragma unroll
    for (int r = 0; r < 4; ++r) {
      size_t prow = (size_t)(rbase + m * 16 + r) * IDIM;
#pragma unroll
      for (int n = 0; n < 4; ++n) {
        float g = clamp500(accg[m][n][r]);
        float u = clamp500(accu[m][n][r]);
        float sl = g / (1.f + __expf(-g));
        float p = clamp500(sl * u);
        P[prow + cbase + n * 16] = f2bf(p);
      }
    }
  }
}

// ---------------- GEMM2: slot = weight * clamp(P*Wd^T)  (shared: clamp(clamp(.)*sig)) ----------------
__global__ __launch_bounds__(256) void gemm2_kernel(
    const unsigned short* __restrict__ P,
    const unsigned short* __restrict__ wd_all,
    float* __restrict__ slot,
    const int* __restrict__ meta, const float* __restrict__ lw,
    const float* __restrict__ sgate) {
  int mt = blockIdx.y, nt = blockIdx.x;
  if (mt >= meta[48]) return;
  int ex = meta[64 + mt];
  int r0 = meta[192 + mt];
  __shared__ unsigned short sA[128 * 64], sB[128 * 64];
  int tid = threadIdx.x, lane = tid & 63, wv = tid >> 6;
  int wr = wv >> 1, wc = wv & 1;
  int ar = tid >> 3;
  int ac = (tid & 7) * 8;
  const unsigned short* wd = wd_all + (size_t)ex * EXP_W_ELEMS;
  int n0 = nt * 128;
  f32x4 zero = {0.f, 0.f, 0.f, 0.f};
  f32x4 acc[4][4];
#pragma unroll
  for (int m = 0; m < 4; ++m)
#pragma unroll
    for (int n = 0; n < 4; ++n) acc[m][n] = zero;

  for (int k0 = 0; k0 < IDIM; k0 += 64) {
    __syncthreads();
#pragma unroll
    for (int c = 0; c < 4; ++c) {
      int lr = c * 32 + ar;
      ld_g2l_16(P + (size_t)(r0 + lr) * IDIM + k0 + ac, &sA[lr * 64 + ac]);
      ld_g2l_16(wd + (size_t)(n0 + lr) * IDIM + k0 + ac, &sB[lr * 64 + ac]);
    }
    __syncthreads();
#pragma unroll
    for (int kk = 0; kk < 2; ++kk) {
      int ko = kk * 32 + (lane >> 4) * 8;
      bf16x8 af[4], bfr[4];
#pragma unroll
      for (int m = 0; m < 4; ++m)
        af[m] = *(const bf16x8*)&sA[(wr * 64 + m * 16 + (lane & 15)) * 64 + ko];
#pragma unroll
      for (int n = 0; n < 4; ++n)
        bfr[n] = *(const bf16x8*)&sB[(wc * 64 + n * 16 + (lane & 15)) * 64 + ko];
#pragma unroll
      for (int m = 0; m < 4; ++m)
#pragma unroll
        for (int n = 0; n < 4; ++n)
          acc[m][n] = mfma16(af[m], bfr[n], acc[m][n]);
    }
  }
  float gsig = 1.f / (1.f + __expf(-sgate[0]));
  int rbase = r0 + wr * 64 + (lane >> 4) * 4;
  int cbase = n0 + wc * 64 + (lane & 15);
#pragma unroll
  for (int m = 0; m < 4; ++m) {
#pragma unroll
    for (int r = 0; r < 4; ++r) {
      int row = rbase + m * 16 + r;
      float wgt = (ex == 8) ? 1.f : lw[row];
      size_t srow = (size_t)row * HDIM;
#pragma unroll
      for (int n = 0; n < 4; ++n) {
        float o = clamp500(acc[m][n][r]);
        float val = (ex == 8) ? clamp500(o * gsig) : wgt * o;
        slot[srow + cbase + n * 16] = val;
      }
    }
  }
}

// ---------------- combine: final = clamp(slot0 + slot1 + shared) ----------------
__global__ __launch_bounds__(256) void combine_kernel(
    const float* __restrict__ slot, const int* __restrict__ rowslot,
    const int* __restrict__ meta, float* __restrict__ out) {
  int i = blockIdx.x * 256 + threadIdx.x;  // float4 index
  int t = i >> 8;
  int c = (i & 255) * 4;
  int sb = meta[16 + 8];
  int r0 = rowslot[2 * t], r1 = rowslot[2 * t + 1];
  float4 va = *(const float4*)(slot + (size_t)r0 * HDIM + c);
  float4 vb = *(const float4*)(slot + (size_t)r1 * HDIM + c);
  float4 vs = *(const float4*)(slot + (size_t)(sb + t) * HDIM + c);
  float4 o;
  o.x = clamp500(va.x + vb.x + vs.x);
  o.y = clamp500(va.y + vb.y + vs.y);
  o.z = clamp500(va.z + vb.z + vs.z);
  o.w = clamp500(va.w + vb.w + vs.w);
  *(float4*)(out + (size_t)t * HDIM + c) = o;
}

// ---------------- launch ----------------
extern "C" void kernel_launch(void* const* d_in, const int* in_sizes, int n_in,
                              void* d_out, int out_size, void* d_ws, size_t ws_size,
                              hipStream_t stream) {
  const float* x     = (const float*)d_in[0];
  const float* lnw   = (const float*)d_in[1];
  const float* lnb   = (const float*)d_in[2];
  const float* rw    = (const float*)d_in[3];
  const float* wg_f  = (const float*)d_in[4];
  const float* wu_f  = (const float*)d_in[5];
  const float* wd_f  = (const float*)d_in[6];
  const float* swg_f = (const float*)d_in[7];
  const float* swu_f = (const float*)d_in[8];
  const float* swd_f = (const float*)d_in[9];
  const float* sgate = (const float*)d_in[10];
  float* out = (float*)d_out;

  char* ws = (char*)d_ws;
  unsigned short* wgb = (unsigned short*)(ws + OFF_WG);
  unsigned short* wub = (unsigned short*)(ws + OFF_WU);
  unsigned short* wdb = (unsigned short*)(ws + OFF_WD);
  unsigned short* hf  = (unsigned short*)(ws + OFF_HF);
  unsigned short* P   = (unsigned short*)(ws + OFF_P);
  float* slot    = (float*)(ws + OFF_SLOT);
  int*   top_i   = (int*)(ws + OFF_TOPI);
  float* top_w   = (float*)(ws + OFF_TOPW);
  float* probs   = (float*)(ws + OFF_PROB);
  float* zent    = (float*)(ws + OFF_ZENT);
  int*   meta    = (int*)(ws + OFF_META);
  int*   ltok    = (int*)(ws + OFF_LTOK);
  float* lw      = (float*)(ws + OFF_LW);
  int*   rowslot = (int*)(ws + OFF_ROWS);

  // weights fp32 -> bf16 (experts 0..7 from dense arrays, shared as expert 8)
  cvt_kernel<<<2048, 256, 0, stream>>>(wg_f, wgb, (int)(8 * EXP_W_ELEMS / 4));
  cvt_kernel<<<2048, 256, 0, stream>>>(wu_f, wub, (int)(8 * EXP_W_ELEMS / 4));
  cvt_kernel<<<2048, 256, 0, stream>>>(wd_f, wdb, (int)(8 * EXP_W_ELEMS / 4));
  cvt_kernel<<<512, 256, 0, stream>>>(swg_f, wgb + 8 * EXP_W_ELEMS, (int)(EXP_W_ELEMS / 4));
  cvt_kernel<<<512, 256, 0, stream>>>(swu_f, wub + 8 * EXP_W_ELEMS, (int)(EXP_W_ELEMS / 4));
  cvt_kernel<<<512, 256, 0, stream>>>(swd_f, wdb + 8 * EXP_W_ELEMS, (int)(EXP_W_ELEMS / 4));

  router_kernel<<<TTOK / 4, 256, 0, stream>>>(x, lnw, lnb, rw, hf, top_i, top_w, probs, zent);
  aux_kernel<<<1, 256, 0, stream>>>(top_i, probs, zent, meta, ltok, lw, out + (size_t)TTOK * HDIM);
  scatter_kernel<<<32, 256, 0, stream>>>(top_i, top_w, meta, ltok, lw, rowslot);

  gemm1_kernel<<<dim3(16, MT_MAX), 256, 0, stream>>>(hf, wgb, wub, P, meta, ltok);
  gemm2_kernel<<<dim3(8, MT_MAX), 256, 0, stream>>>(P, wdb, slot, meta, lw, sgate);
  combine_kernel<<<TTOK * HDIM / 4 / 256, 256, 0, stream>>>(slot, rowslot, meta, out);
}

// Round 3
// 358.290 us; speedup vs baseline: 2.8043x; 1.3963x over previous
//
#include <hip/hip_runtime.h>
#include <hip/hip_bf16.h>
#include <cstdint>
#include <cstddef>

// ---------------- types ----------------
typedef __attribute__((ext_vector_type(8))) short bf16x8;
typedef __attribute__((ext_vector_type(4))) float f32x4;

#define HDIM 1024
#define IDIM 2048
#define TTOK 4096
#define NEXP 8
#define ROWS_PAD 14336          // 256-padded routed (<=10240) + shared 4096
#define MT_MAX 64               // max 256-row m-tiles: <=40 routed + 16 shared
#define EXP_W_ELEMS 2097152ull  // 2048*1024 per weight matrix per expert

// ---------------- workspace layout (bytes) ----------------
#define OFF_WG   0ull
#define OFF_WU   (OFF_WG + 9ull * EXP_W_ELEMS * 2ull)
#define OFF_WD   (OFF_WU + 9ull * EXP_W_ELEMS * 2ull)
#define OFF_HF   (OFF_WD + 9ull * EXP_W_ELEMS * 2ull)            // [4096][1024] bf16
#define OFF_P    (OFF_HF + 4096ull * 1024ull * 2ull)             // [ROWS_PAD][2048] bf16
#define OFF_SLOT (OFF_P  + (size_t)ROWS_PAD * 2048ull * 2ull)    // [ROWS_PAD][1024] f32
#define OFF_TOPI (OFF_SLOT + (size_t)ROWS_PAD * 1024ull * 4ull)  // [8192] int
#define OFF_TOPW (OFF_TOPI + 8192ull * 4ull)                     // [8192] f32
#define OFF_PROB (OFF_TOPW + 8192ull * 4ull)                     // [4096][8] f32
#define OFF_ZENT (OFF_PROB + 4096ull * 8ull * 4ull)              // [4096][2] f32
#define OFF_META (OFF_ZENT + 4096ull * 2ull * 4ull)              // ints, see below
#define OFF_LTOK (OFF_META + 4096ull)                            // [ROWS_PAD] int
#define OFF_LW   (OFF_LTOK + (size_t)ROWS_PAD * 4ull)            // [ROWS_PAD] f32
#define OFF_ROWS (OFF_LW + (size_t)ROWS_PAD * 4ull)              // [8192] int

// meta (ints): [0..8]=cnt, [16..24]=256-padded base, [32..40]=cursor,
//              [48]=ntiles256, [64..127]=tile->expert, [128..191]=tile->row0

#define VM_WAIT(n) asm volatile("s_waitcnt vmcnt(" #n ")" ::: "memory")
#define SBAR __builtin_amdgcn_s_barrier()
#define FENCE __builtin_amdgcn_sched_barrier(0)
#define PRIO_HI __builtin_amdgcn_s_setprio(1)
#define PRIO_LO __builtin_amdgcn_s_setprio(0)

__device__ __forceinline__ float clamp500(float v) {
  return fminf(fmaxf(v, -500.f), 500.f);
}

__device__ __forceinline__ unsigned short f2bf(float f) {
  unsigned int u = __float_as_uint(f);
  u += 0x7FFFu + ((u >> 16) & 1u);  // RNE; inputs always finite here
  return (unsigned short)(u >> 16);
}

// async global->LDS, 16B per lane. LDS dest must be wave-uniform base + lane*16.
__device__ __forceinline__ void stage16(const unsigned short* g, unsigned short* l) {
  __builtin_amdgcn_global_load_lds(
      (const __attribute__((address_space(1))) void*)g,
      (__attribute__((address_space(3))) void*)l, 16, 0, 0);
}

__device__ __forceinline__ f32x4 mfma16(bf16x8 a, bf16x8 b, f32x4 c) {
  return __builtin_amdgcn_mfma_f32_16x16x32_bf16(a, b, c, 0, 0, 0);
}

// ---------------- fp32 -> bf16 weight conversion ----------------
__global__ __launch_bounds__(256) void cvt_kernel(const float* __restrict__ src,
                                                  unsigned short* __restrict__ dst,
                                                  int n4) {
  int i = blockIdx.x * 256 + threadIdx.x;
  int stride = gridDim.x * 256;
  for (; i < n4; i += stride) {
    float4 f = ((const float4*)src)[i];
    uint2 pk;
    pk.x = (unsigned)f2bf(f.x) | ((unsigned)f2bf(f.y) << 16);
    pk.y = (unsigned)f2bf(f.z) | ((unsigned)f2bf(f.w) << 16);
    ((uint2*)dst)[i] = pk;
  }
}

// ---------------- router: LN -> logits -> softmax -> top2 + aux terms ----------------
__global__ __launch_bounds__(256) void router_kernel(
    const float* __restrict__ x, const float* __restrict__ lnw,
    const float* __restrict__ lnb, const float* __restrict__ rw,
    unsigned short* __restrict__ hf, int* __restrict__ top_i,
    float* __restrict__ top_w, float* __restrict__ probs_tok,
    float* __restrict__ zent) {
  int wv = threadIdx.x >> 6, lane = threadIdx.x & 63;
  int t = blockIdx.x * 4 + wv;  // one wave per token
  const float* xr = x + (size_t)t * HDIM;
  float v[16];
  float s = 0.f;
#pragma unroll
  for (int j = 0; j < 16; ++j) {
    int h = j * 64 + lane;
    float f = clamp500(xr[h]);
    v[j] = f;
    hf[(size_t)t * HDIM + h] = f2bf(f);
    s += f;
  }
#pragma unroll
  for (int m = 32; m; m >>= 1) s += __shfl_xor(s, m);
  float mu = s * (1.f / HDIM);
  float s2 = 0.f;
#pragma unroll
  for (int j = 0; j < 16; ++j) { float d = v[j] - mu; s2 += d * d; }
#pragma unroll
  for (int m = 32; m; m >>= 1) s2 += __shfl_xor(s2, m);
  float rstd = rsqrtf(s2 * (1.f / HDIM) + 1e-5f);
  float acc[8];
#pragma unroll
  for (int e = 0; e < 8; ++e) acc[e] = 0.f;
#pragma unroll
  for (int j = 0; j < 16; ++j) {
    int h = j * 64 + lane;
    float hn = (v[j] - mu) * rstd * lnw[h] + lnb[h];
    hn = fminf(fmaxf(hn, -50.f), 50.f);
#pragma unroll
    for (int e = 0; e < 8; ++e) acc[e] += hn * rw[e * HDIM + h];
  }
#pragma unroll
  for (int e = 0; e < 8; ++e) {
    float a = acc[e];
#pragma unroll
    for (int m = 32; m; m >>= 1) a += __shfl_xor(a, m);
    acc[e] = a;
  }
  if (lane == 0) {
    float lg[8], mx = -1e30f;
#pragma unroll
    for (int e = 0; e < 8; ++e) {
      float l = fminf(fmaxf(acc[e], -10.f), 10.f);
      lg[e] = l;
      mx = fmaxf(mx, l);
    }
    float se = 0.f;
    float ex[8];
#pragma unroll
    for (int e = 0; e < 8; ++e) { ex[e] = expf(lg[e] - mx); se += ex[e]; }
    float inv = 1.f / se;
    float pr[8];
#pragma unroll
    for (int e = 0; e < 8; ++e) {
      float p = ex[e] * inv;
      pr[e] = fminf(fmaxf(p, 1e-4f), 1.f);
      probs_tok[t * 8 + e] = pr[e];
    }
    int i0 = 0; float v0 = pr[0];
#pragma unroll
    for (int e = 1; e < 8; ++e) if (pr[e] > v0) { v0 = pr[e]; i0 = e; }
    int i1 = -1; float v1 = -1.f;
#pragma unroll
    for (int e = 0; e < 8; ++e) if (e != i0 && pr[e] > v1) { v1 = pr[e]; i1 = e; }
    float dsum = fmaxf(v0 + v1, 1e-4f);
    top_i[2 * t] = i0; top_i[2 * t + 1] = i1;
    top_w[2 * t] = v0 / dsum; top_w[2 * t + 1] = v1 / dsum;
    float lse = mx + logf(se);
    zent[2 * t] = lse * lse;
    float ent = 0.f;
#pragma unroll
    for (int e = 0; e < 8; ++e) {
      float ps = fminf(fmaxf(pr[e], 1e-4f), 1.f - 1e-4f);
      ent -= ps * logf(ps);
    }
    zent[2 * t + 1] = ent;
  }
}

// ---------------- aux loss + 256-padded tile map (single block, deterministic) ----------------
__global__ __launch_bounds__(256) void aux_kernel(
    const int* __restrict__ top_i, const float* __restrict__ probs_tok,
    const float* __restrict__ zent, int* __restrict__ meta,
    int* __restrict__ ltok, float* __restrict__ lw,
    float* __restrict__ aux_out) {
  __shared__ int sc[8];
  __shared__ float red[256];
  __shared__ float sums[10];
  int tid = threadIdx.x;
  if (tid < 8) sc[tid] = 0;
  __syncthreads();
  for (int s = tid; s < 8192; s += 256) atomicAdd(&sc[top_i[s]], 1);
  // default-init padded token lists (scatter overwrites the live ones)
  for (int i = tid; i < ROWS_PAD; i += 256) { ltok[i] = 0; lw[i] = 0.f; }
  float pe[8] = {0, 0, 0, 0, 0, 0, 0, 0};
  float zs = 0.f, es = 0.f;
  for (int t = tid; t < 4096; t += 256) {
#pragma unroll
    for (int e = 0; e < 8; ++e) pe[e] += probs_tok[t * 8 + e];
    zs += zent[2 * t];
    es += zent[2 * t + 1];
  }
  for (int e = 0; e < 10; ++e) {
    float val = (e < 8) ? pe[e] : ((e == 8) ? zs : es);
    red[tid] = val;
    __syncthreads();
    for (int off = 128; off; off >>= 1) {
      if (tid < off) red[tid] += red[tid + off];
      __syncthreads();
    }
    if (tid == 0) sums[e] = red[0];
    __syncthreads();
  }
  if (tid == 0) {
    float lb = 0.f, usage = 0.f;
    for (int e = 0; e < 8; ++e) {
      float tpe = (float)sc[e] / 8192.f;
      float avg = sums[e] / 4096.f;
      lb += tpe * avg;
      usage += (tpe > 0.01f) ? 1.f : 0.f;
    }
    lb *= 8.f;
    float z_loss = (sums[8] / 4096.f) * 0.001f;
    float ent_loss = fmaxf(logf(8.f) - sums[9] / 4096.f, 0.f) * 0.01f;
    float util = (1.f - usage / 8.f) * 0.1f;
    float aux = fminf(fmaxf(lb + z_loss + ent_loss + util, 0.f), 10.f);
    *aux_out = aux;
    // 256-padded tile map
    int base = 0, tct = 0;
    for (int e = 0; e < 8; ++e) {
      int cnt = sc[e];
      meta[e] = cnt;
      meta[16 + e] = base;
      meta[32 + e] = 0;
      int nt = (cnt + 255) >> 8;
      for (int i = 0; i < nt; ++i) { meta[64 + tct] = e; meta[128 + tct] = base + i * 256; ++tct; }
      base += nt * 256;
    }
    meta[8] = TTOK;           // shared "expert"
    meta[16 + 8] = base;      // shared padded base
    meta[32 + 8] = 0;
    for (int i = 0; i < 16; ++i) { meta[64 + tct] = 8; meta[128 + tct] = base + i * 256; ++tct; }
    meta[48] = tct;
  }
}

// ---------------- scatter tokens into per-expert padded lists ----------------
__global__ __launch_bounds__(256) void scatter_kernel(
    const int* __restrict__ top_i, const float* __restrict__ top_w,
    int* __restrict__ meta, int* __restrict__ ltok, float* __restrict__ lw,
    int* __restrict__ rowslot) {
  int s = blockIdx.x * 256 + threadIdx.x;
  if (s < 8192) {
    int e = top_i[s];
    int pos = atomicAdd(&meta[32 + e], 1);
    int idx = meta[16 + e] + pos;
    ltok[idx] = s >> 1;
    lw[idx] = top_w[s];
    rowslot[s] = idx;
  }
  if (s < TTOK) {  // identity list for shared expert
    int sb = meta[16 + 8];
    ltok[sb + s] = s;
    lw[sb + s] = 1.f;
  }
}

// ---------------- GEMM1: P = clamp(silu(clamp(A*Wg^T)) * clamp(A*Wu^T)) ----------------
// BM=256, BN=128 (G and U), BK=64, 8 waves (2x4), 8-phase-style schedule,
// both-sides XOR swizzle, counted vmcnt(2), 128KB dynamic LDS double-buffered.
__global__ __launch_bounds__(512, 1) void gemm1_kernel(
    const unsigned short* __restrict__ hf,
    const unsigned short* __restrict__ wg_all,
    const unsigned short* __restrict__ wu_all,
    unsigned short* __restrict__ P,
    const int* __restrict__ meta, const int* __restrict__ ltok) {
  int mt = blockIdx.y, nt = blockIdx.x;
  if (mt >= meta[48]) return;
  int ex = meta[64 + mt];
  int r0 = meta[128 + mt];
  extern __shared__ unsigned short lds[];
  unsigned short* sA = lds;          // 2 x 16384 elems (256x64)
  unsigned short* sG = lds + 32768;  // 2 x 8192  (128x64)
  unsigned short* sU = lds + 49152;  // 2 x 8192
  int tid = threadIdx.x, lane = tid & 63, wv = tid >> 6;
  int wr = wv >> 2, wc = wv & 3;
  int l15 = lane & 15, l4 = lane >> 4;
  int srow = tid >> 3;              // staging row within a 64-row issue
  int gch = (tid & 7) ^ (srow & 7); // inverse-swizzled source 16B chunk
  int ldst = tid * 8;               // linear LDS dest elems within an issue
  const unsigned short* wg = wg_all + (size_t)ex * EXP_W_ELEMS;
  const unsigned short* wu = wu_all + (size_t)ex * EXP_W_ELEMS;
  int n0 = nt * 128;
  const unsigned short* srcA[4];
#pragma unroll
  for (int i = 0; i < 4; ++i) {
    int tok = ltok[r0 + i * 64 + srow];
    srcA[i] = hf + (size_t)tok * HDIM + gch * 8;
  }
  const unsigned short* srcG[2];
  const unsigned short* srcU[2];
#pragma unroll
  for (int i = 0; i < 2; ++i) {
    srcG[i] = wg + (size_t)(n0 + i * 64 + srow) * HDIM + gch * 8;
    srcU[i] = wu + (size_t)(n0 + i * 64 + srow) * HDIM + gch * 8;
  }
  // swizzled ds_read chunk per kk (row&7 == lane&7 for all frag rows)
  int ch0 = (0 + l4) ^ (lane & 7);
  int ch1 = (4 + l4) ^ (lane & 7);
  int baseA = (wr * 128 + l15) * 64;
  int baseG = (wc * 32 + l15) * 64;

  f32x4 zero = {0.f, 0.f, 0.f, 0.f};
  f32x4 accg[8][2], accu[8][2];
#pragma unroll
  for (int m = 0; m < 8; ++m)
#pragma unroll
    for (int n = 0; n < 2; ++n) { accg[m][n] = zero; accu[m][n] = zero; }

  // prologue: stage K-step 0 into buf0, drain, barrier
#pragma unroll
  for (int i = 0; i < 4; ++i) stage16(srcA[i], &sA[i * 4096 + ldst]);
#pragma unroll
  for (int i = 0; i < 2; ++i) stage16(srcG[i], &sG[i * 4096 + ldst]);
#pragma unroll
  for (int i = 0; i < 2; ++i) stage16(srcU[i], &sU[i * 4096 + ldst]);
  VM_WAIT(0);
  SBAR; FENCE;

  for (int t = 0; t < 16; ++t) {
    int cur = t & 1, nxt = cur ^ 1;
    int cbA = cur * 16384, cbG = cur * 8192;
    int nbA = nxt * 16384, nbG = nxt * 8192;
    int k1 = (t + 1) * 64;
    bool pre = (t < 15);
    bf16x8 af[8], gf[2], uf[2];
    // ---- iter top: stage A0,A1 for t+1; counted vmcnt; converge ----
    if (pre) {
      stage16(srcA[0] + k1, &sA[nbA + 0 * 4096 + ldst]);
      stage16(srcA[1] + k1, &sA[nbA + 1 * 4096 + ldst]);
      VM_WAIT(2);
    } else {
      VM_WAIT(0);
    }
    SBAR; FENCE;
    // ---- phase 0: kk0, G ----
#pragma unroll
    for (int m = 0; m < 8; ++m)
      af[m] = *(const bf16x8*)&sA[cbA + baseA + m * 1024 + ch0 * 8];
#pragma unroll
    for (int n = 0; n < 2; ++n)
      gf[n] = *(const bf16x8*)&sG[cbG + baseG + n * 1024 + ch0 * 8];
    SBAR; FENCE;
    PRIO_HI;
#pragma unroll
    for (int m = 0; m < 8; ++m)
#pragma unroll
      for (int n = 0; n < 2; ++n)
        accg[m][n] = mfma16(af[m], gf[n], accg[m][n]);
    PRIO_LO;
    SBAR; FENCE;
    // ---- phase 1: kk0, U ----
    if (pre) {
      stage16(srcA[2] + k1, &sA[nbA + 2 * 4096 + ldst]);
      stage16(srcA[3] + k1, &sA[nbA + 3 * 4096 + ldst]);
    }
#pragma unroll
    for (int n = 0; n < 2; ++n)
      uf[n] = *(const bf16x8*)&sU[cbG + baseG + n * 1024 + ch0 * 8];
    SBAR; FENCE;
    PRIO_HI;
#pragma unroll
    for (int m = 0; m < 8; ++m)
#pragma unroll
      for (int n = 0; n < 2; ++n)
        accu[m][n] = mfma16(af[m], uf[n], accu[m][n]);
    PRIO_LO;
    SBAR; FENCE;
    // ---- phase 2: kk1, G ----
    if (pre) {
      stage16(srcG[0] + k1, &sG[nbG + 0 * 4096 + ldst]);
      stage16(srcG[1] + k1, &sG[nbG + 1 * 4096 + ldst]);
    }
#pragma unroll
    for (int m = 0; m < 8; ++m)
      af[m] = *(const bf16x8*)&sA[cbA + baseA + m * 1024 + ch1 * 8];
#pragma unroll
    for (int n = 0; n < 2; ++n)
      gf[n] = *(const bf16x8*)&sG[cbG + baseG + n * 1024 + ch1 * 8];
    SBAR; FENCE;
    PRIO_HI;
#pragma unroll
    for (int m = 0; m < 8; ++m)
#pragma unroll
      for (int n = 0; n < 2; ++n)
        accg[m][n] = mfma16(af[m], gf[n], accg[m][n]);
    PRIO_LO;
    SBAR; FENCE;
    // ---- phase 3: kk1, U ----
    if (pre) {
      stage16(srcU[0] + k1, &sU[nbG + 0 * 4096 + ldst]);
      stage16(srcU[1] + k1, &sU[nbG + 1 * 4096 + ldst]);
    }
#pragma unroll
    for (int n = 0; n < 2; ++n)
      uf[n] = *(const bf16x8*)&sU[cbG + baseG + n * 1024 + ch1 * 8];
    SBAR; FENCE;
    PRIO_HI;
#pragma unroll
    for (int m = 0; m < 8; ++m)
#pragma unroll
      for (int n = 0; n < 2; ++n)
        accu[m][n] = mfma16(af[m], uf[n], accu[m][n]);
    PRIO_LO;
    SBAR; FENCE;
  }
  // epilogue: SwiGLU, write bf16 P (padded rows junk, never read)
  int rbase = r0 + wr * 128 + l4 * 4;
  int cbase = n0 + wc * 32 + l15;
#pragma unroll
  for (int m = 0; m < 8; ++m) {
#pragma unroll
    for (int r = 0; r < 4; ++r) {
      size_t prow = (size_t)(rbase + m * 16 + r) * IDIM;
#pragma unroll
      for (int n = 0; n < 2; ++n) {
        float g = clamp500(accg[m][n][r]);
        float u = clamp500(accu[m][n][r]);
        float sl = g / (1.f + __expf(-g));
        float p = clamp500(sl * u);
        P[prow + cbase + n * 16] = f2bf(p);
      }
    }
  }
}

// ---------------- GEMM2: slot = weight * clamp(P*Wd^T)  (shared: clamp(clamp(.)*sig)) ----------------
// BM=256, BN=256, BK=64, 8 waves (2x4), same schedule as gemm1.
__global__ __launch_bounds__(512, 1) void gemm2_kernel(
    const unsigned short* __restrict__ P,
    const unsigned short* __restrict__ wd_all,
    float* __restrict__ slot,
    const int* __restrict__ meta, const float* __restrict__ lw,
    const float* __restrict__ sgate) {
  int mt = blockIdx.y, nt = blockIdx.x;
  if (mt >= meta[48]) return;
  int ex = meta[64 + mt];
  int r0 = meta[128 + mt];
  extern __shared__ unsigned short lds[];
  unsigned short* sA = lds;          // 2 x 16384 (256x64)
  unsigned short* sB = lds + 32768;  // 2 x 16384 (256x64)
  int tid = threadIdx.x, lane = tid & 63, wv = tid >> 6;
  int wr = wv >> 2, wc = wv & 3;
  int l15 = lane & 15, l4 = lane >> 4;
  int srow = tid >> 3;
  int gch = (tid & 7) ^ (srow & 7);
  int ldst = tid * 8;
  const unsigned short* wd = wd_all + (size_t)ex * EXP_W_ELEMS;
  int n0 = nt * 256;
  const unsigned short* srcA[4];
  const unsigned short* srcB[4];
#pragma unroll
  for (int i = 0; i < 4; ++i) {
    srcA[i] = P + (size_t)(r0 + i * 64 + srow) * IDIM + gch * 8;
    srcB[i] = wd + (size_t)(n0 + i * 64 + srow) * IDIM + gch * 8;
  }
  int ch0 = (0 + l4) ^ (lane & 7);
  int ch1 = (4 + l4) ^ (lane & 7);
  int baseA = (wr * 128 + l15) * 64;
  int baseB = (wc * 64 + l15) * 64;

  f32x4 zero = {0.f, 0.f, 0.f, 0.f};
  f32x4 acc[8][4];
#pragma unroll
  for (int m = 0; m < 8; ++m)
#pragma unroll
    for (int n = 0; n < 4; ++n) acc[m][n] = zero;

#pragma unroll
  for (int i = 0; i < 4; ++i) stage16(srcA[i], &sA[i * 4096 + ldst]);
#pragma unroll
  for (int i = 0; i < 4; ++i) stage16(srcB[i], &sB[i * 4096 + ldst]);
  VM_WAIT(0);
  SBAR; FENCE;

  for (int t = 0; t < 32; ++t) {
    int cur = t & 1, nxt = cur ^ 1;
    int cb = cur * 16384, nb = nxt * 16384;
    int k1 = (t + 1) * 64;
    bool pre = (t < 31);
    bf16x8 af[8], bfr[4];
    // ---- iter top ----
    if (pre) {
      stage16(srcA[0] + k1, &sA[nb + 0 * 4096 + ldst]);
      stage16(srcA[1] + k1, &sA[nb + 1 * 4096 + ldst]);
      VM_WAIT(2);
    } else {
      VM_WAIT(0);
    }
    SBAR; FENCE;
    // ---- phase 0: kk0, n01 ----
#pragma unroll
    for (int m = 0; m < 8; ++m)
      af[m] = *(const bf16x8*)&sA[cb + baseA + m * 1024 + ch0 * 8];
#pragma unroll
    for (int n = 0; n < 2; ++n)
      bfr[n] = *(const bf16x8*)&sB[cb + baseB + n * 1024 + ch0 * 8];
    SBAR; FENCE;
    PRIO_HI;
#pragma unroll
    for (int m = 0; m < 8; ++m)
#pragma unroll
      for (int n = 0; n < 2; ++n)
        acc[m][n] = mfma16(af[m], bfr[n], acc[m][n]);
    PRIO_LO;
    SBAR; FENCE;
    // ---- phase 1: kk0, n23 ----
    if (pre) {
      stage16(srcA[2] + k1, &sA[nb + 2 * 4096 + ldst]);
      stage16(srcA[3] + k1, &sA[nb + 3 * 4096 + ldst]);
    }
#pragma unroll
    for (int n = 2; n < 4; ++n)
      bfr[n] = *(const bf16x8*)&sB[cb + baseB + n * 1024 + ch0 * 8];
    SBAR; FENCE;
    PRIO_HI;
#pragma unroll
    for (int m = 0; m < 8; ++m)
#pragma unroll
      for (int n = 2; n < 4; ++n)
        acc[m][n] = mfma16(af[m], bfr[n], acc[m][n]);
    PRIO_LO;
    SBAR; FENCE;
    // ---- phase 2: kk1, n01 ----
    if (pre) {
      stage16(srcB[0] + k1, &sB[nb + 0 * 4096 + ldst]);
      stage16(srcB[1] + k1, &sB[nb + 1 * 4096 + ldst]);
    }
#pragma unroll
    for (int m = 0; m < 8; ++m)
      af[m] = *(const bf16x8*)&sA[cb + baseA + m * 1024 + ch1 * 8];
#pragma unroll
    for (int n = 0; n < 2; ++n)
      bfr[n] = *(const bf16x8*)&sB[cb + baseB + n * 1024 + ch1 * 8];
    SBAR; FENCE;
    PRIO_HI;
#pragma unroll
    for (int m = 0; m < 8; ++m)
#pragma unroll
      for (int n = 0; n < 2; ++n)
        acc[m][n] = mfma16(af[m], bfr[n], acc[m][n]);
    PRIO_LO;
    SBAR; FENCE;
    // ---- phase 3: kk1, n23 ----
    if (pre) {
      stage16(srcB[2] + k1, &sB[nb + 2 * 4096 + ldst]);
      stage16(srcB[3] + k1, &sB[nb + 3 * 4096 + ldst]);
    }
#pragma unroll
    for (int n = 2; n < 4; ++n)
      bfr[n] = *(const bf16x8*)&sB[cb + baseB + n * 1024 + ch1 * 8];
    SBAR; FENCE;
    PRIO_HI;
#pragma unroll
    for (int m = 0; m < 8; ++m)
#pragma unroll
      for (int n = 2; n < 4; ++n)
        acc[m][n] = mfma16(af[m], bfr[n], acc[m][n]);
    PRIO_LO;
    SBAR; FENCE;
  }
  float gsig = 1.f / (1.f + __expf(-sgate[0]));
  int rbase = r0 + wr * 128 + l4 * 4;
  int cbase = n0 + wc * 64 + l15;
#pragma unroll
  for (int m = 0; m < 8; ++m) {
#pragma unroll
    for (int r = 0; r < 4; ++r) {
      int row = rbase + m * 16 + r;
      float wgt = (ex == 8) ? 1.f : lw[row];
      size_t srow_o = (size_t)row * HDIM;
#pragma unroll
      for (int n = 0; n < 4; ++n) {
        float o = clamp500(acc[m][n][r]);
        float val = (ex == 8) ? clamp500(o * gsig) : wgt * o;
        slot[srow_o + cbase + n * 16] = val;
      }
    }
  }
}

// ---------------- combine: final = clamp(slot0 + slot1 + shared) ----------------
__global__ __launch_bounds__(256) void combine_kernel(
    const float* __restrict__ slot, const int* __restrict__ rowslot,
    const int* __restrict__ meta, float* __restrict__ out) {
  int i = blockIdx.x * 256 + threadIdx.x;  // float4 index
  int t = i >> 8;
  int c = (i & 255) * 4;
  int sb = meta[16 + 8];
  int r0 = rowslot[2 * t], r1 = rowslot[2 * t + 1];
  float4 va = *(const float4*)(slot + (size_t)r0 * HDIM + c);
  float4 vb = *(const float4*)(slot + (size_t)r1 * HDIM + c);
  float4 vs = *(const float4*)(slot + (size_t)(sb + t) * HDIM + c);
  float4 o;
  o.x = clamp500(va.x + vb.x + vs.x);
  o.y = clamp500(va.y + vb.y + vs.y);
  o.z = clamp500(va.z + vb.z + vs.z);
  o.w = clamp500(va.w + vb.w + vs.w);
  *(float4*)(out + (size_t)t * HDIM + c) = o;
}

// ---------------- launch ----------------
extern "C" void kernel_launch(void* const* d_in, const int* in_sizes, int n_in,
                              void* d_out, int out_size, void* d_ws, size_t ws_size,
                              hipStream_t stream) {
  const float* x     = (const float*)d_in[0];
  const float* lnw   = (const float*)d_in[1];
  const float* lnb   = (const float*)d_in[2];
  const float* rw    = (const float*)d_in[3];
  const float* wg_f  = (const float*)d_in[4];
  const float* wu_f  = (const float*)d_in[5];
  const float* wd_f  = (const float*)d_in[6];
  const float* swg_f = (const float*)d_in[7];
  const float* swu_f = (const float*)d_in[8];
  const float* swd_f = (const float*)d_in[9];
  const float* sgate = (const float*)d_in[10];
  float* out = (float*)d_out;

  char* ws = (char*)d_ws;
  unsigned short* wgb = (unsigned short*)(ws + OFF_WG);
  unsigned short* wub = (unsigned short*)(ws + OFF_WU);
  unsigned short* wdb = (unsigned short*)(ws + OFF_WD);
  unsigned short* hf  = (unsigned short*)(ws + OFF_HF);
  unsigned short* P   = (unsigned short*)(ws + OFF_P);
  float* slot    = (float*)(ws + OFF_SLOT);
  int*   top_i   = (int*)(ws + OFF_TOPI);
  float* top_w   = (float*)(ws + OFF_TOPW);
  float* probs   = (float*)(ws + OFF_PROB);
  float* zent    = (float*)(ws + OFF_ZENT);
  int*   meta    = (int*)(ws + OFF_META);
  int*   ltok    = (int*)(ws + OFF_LTOK);
  float* lw      = (float*)(ws + OFF_LW);
  int*   rowslot = (int*)(ws + OFF_ROWS);

  static int attr_done = 0;
  (void)attr_done;
  hipFuncSetAttribute((const void*)gemm1_kernel,
                      hipFuncAttributeMaxDynamicSharedMemorySize, 131072);
  hipFuncSetAttribute((const void*)gemm2_kernel,
                      hipFuncAttributeMaxDynamicSharedMemorySize, 131072);

  // weights fp32 -> bf16 (experts 0..7 from dense arrays, shared as expert 8)
  cvt_kernel<<<2048, 256, 0, stream>>>(wg_f, wgb, (int)(8 * EXP_W_ELEMS / 4));
  cvt_kernel<<<2048, 256, 0, stream>>>(wu_f, wub, (int)(8 * EXP_W_ELEMS / 4));
  cvt_kernel<<<2048, 256, 0, stream>>>(wd_f, wdb, (int)(8 * EXP_W_ELEMS / 4));
  cvt_kernel<<<512, 256, 0, stream>>>(swg_f, wgb + 8 * EXP_W_ELEMS, (int)(EXP_W_ELEMS / 4));
  cvt_kernel<<<512, 256, 0, stream>>>(swu_f, wub + 8 * EXP_W_ELEMS, (int)(EXP_W_ELEMS / 4));
  cvt_kernel<<<512, 256, 0, stream>>>(swd_f, wdb + 8 * EXP_W_ELEMS, (int)(EXP_W_ELEMS / 4));

  router_kernel<<<TTOK / 4, 256, 0, stream>>>(x, lnw, lnb, rw, hf, top_i, top_w, probs, zent);
  aux_kernel<<<1, 256, 0, stream>>>(top_i, probs, zent, meta, ltok, lw, out + (size_t)TTOK * HDIM);
  scatter_kernel<<<32, 256, 0, stream>>>(top_i, top_w, meta, ltok, lw, rowslot);

  gemm1_kernel<<<dim3(16, MT_MAX), 512, 131072, stream>>>(hf, wgb, wub, P, meta, ltok);
  gemm2_kernel<<<dim3(4, MT_MAX), 512, 131072, stream>>>(P, wdb, slot, meta, lw, sgate);
  combine_kernel<<<TTOK * HDIM / 4 / 256, 256, 0, stream>>>(slot, rowslot, meta, out);
}

// Round 4
// 350.506 us; speedup vs baseline: 2.8665x; 1.0222x over previous
//
#include <hip/hip_runtime.h>
#include <hip/hip_bf16.h>
#include <cstdint>
#include <cstddef>

// ---------------- types ----------------
typedef __attribute__((ext_vector_type(8))) short bf16x8;
typedef __attribute__((ext_vector_type(4))) float f32x4;

#define HDIM 1024
#define IDIM 2048
#define TTOK 4096
#define NEXP 8
#define ROWS_PAD 14336          // 256-padded routed (<=10240) + shared 4096
#define MT_MAX 64               // max 256-row m-tiles: <=40 routed + 16 shared
#define EXP_W_ELEMS 2097152ull  // 2048*1024 per weight matrix per expert

// ---------------- workspace layout (bytes) ----------------
#define OFF_WG   0ull
#define OFF_WU   (OFF_WG + 9ull * EXP_W_ELEMS * 2ull)
#define OFF_WD   (OFF_WU + 9ull * EXP_W_ELEMS * 2ull)
#define OFF_HF   (OFF_WD + 9ull * EXP_W_ELEMS * 2ull)            // [4096][1024] bf16
#define OFF_P    (OFF_HF + 4096ull * 1024ull * 2ull)             // [ROWS_PAD][2048] bf16
#define OFF_SLOT (OFF_P  + (size_t)ROWS_PAD * 2048ull * 2ull)    // [ROWS_PAD][1024] bf16
#define OFF_TOPI (OFF_SLOT + (size_t)ROWS_PAD * 1024ull * 4ull)  // [8192] int
#define OFF_TOPW (OFF_TOPI + 8192ull * 4ull)                     // [8192] f32
#define OFF_PROB (OFF_TOPW + 8192ull * 4ull)                     // [4096][8] f32
#define OFF_ZENT (OFF_PROB + 4096ull * 8ull * 4ull)              // [4096][2] f32
#define OFF_META (OFF_ZENT + 4096ull * 2ull * 4ull)              // ints, see below
#define OFF_LTOK (OFF_META + 4096ull)                            // [ROWS_PAD] int
#define OFF_LW   (OFF_LTOK + (size_t)ROWS_PAD * 4ull)            // [ROWS_PAD] f32
#define OFF_ROWS (OFF_LW + (size_t)ROWS_PAD * 4ull)              // [8192] int

// meta (ints): [0..8]=cnt, [16..24]=256-padded base, [32..40]=cursor,
//              [48]=ntiles256, [64..127]=tile->expert, [128..191]=tile->row0

#define VM_WAIT(n) asm volatile("s_waitcnt vmcnt(" #n ")" ::: "memory")
#define SBAR __builtin_amdgcn_s_barrier()
#define FENCE __builtin_amdgcn_sched_barrier(0)
#define PRIO_HI __builtin_amdgcn_s_setprio(1)
#define PRIO_LO __builtin_amdgcn_s_setprio(0)

__device__ __forceinline__ float clamp500(float v) {
  return fminf(fmaxf(v, -500.f), 500.f);
}

__device__ __forceinline__ unsigned short f2bf(float f) {
  unsigned int u = __float_as_uint(f);
  u += 0x7FFFu + ((u >> 16) & 1u);  // RNE; inputs always finite here
  return (unsigned short)(u >> 16);
}

__device__ __forceinline__ float bf2f(unsigned short u) {
  return __uint_as_float((unsigned)u << 16);
}

// async global->LDS, 16B per lane. LDS dest must be wave-uniform base + lane*16.
__device__ __forceinline__ void stage16(const unsigned short* g, unsigned short* l) {
  __builtin_amdgcn_global_load_lds(
      (const __attribute__((address_space(1))) void*)g,
      (__attribute__((address_space(3))) void*)l, 16, 0, 0);
}

__device__ __forceinline__ f32x4 mfma16(bf16x8 a, bf16x8 b, f32x4 c) {
  return __builtin_amdgcn_mfma_f32_16x16x32_bf16(a, b, c, 0, 0, 0);
}

// ---------------- fp32 -> bf16 weight conversion ----------------
__global__ __launch_bounds__(256) void cvt_kernel(const float* __restrict__ src,
                                                  unsigned short* __restrict__ dst,
                                                  int n4) {
  int i = blockIdx.x * 256 + threadIdx.x;
  int stride = gridDim.x * 256;
  for (; i < n4; i += stride) {
    float4 f = ((const float4*)src)[i];
    uint2 pk;
    pk.x = (unsigned)f2bf(f.x) | ((unsigned)f2bf(f.y) << 16);
    pk.y = (unsigned)f2bf(f.z) | ((unsigned)f2bf(f.w) << 16);
    ((uint2*)dst)[i] = pk;
  }
}

// ---------------- router: LN -> logits -> softmax -> top2 + aux terms ----------------
__global__ __launch_bounds__(256) void router_kernel(
    const float* __restrict__ x, const float* __restrict__ lnw,
    const float* __restrict__ lnb, const float* __restrict__ rw,
    unsigned short* __restrict__ hf, int* __restrict__ top_i,
    float* __restrict__ top_w, float* __restrict__ probs_tok,
    float* __restrict__ zent) {
  int wv = threadIdx.x >> 6, lane = threadIdx.x & 63;
  int t = blockIdx.x * 4 + wv;  // one wave per token
  const float* xr = x + (size_t)t * HDIM;
  float v[16];
  float s = 0.f;
#pragma unroll
  for (int j = 0; j < 16; ++j) {
    int h = j * 64 + lane;
    float f = clamp500(xr[h]);
    v[j] = f;
    hf[(size_t)t * HDIM + h] = f2bf(f);
    s += f;
  }
#pragma unroll
  for (int m = 32; m; m >>= 1) s += __shfl_xor(s, m);
  float mu = s * (1.f / HDIM);
  float s2 = 0.f;
#pragma unroll
  for (int j = 0; j < 16; ++j) { float d = v[j] - mu; s2 += d * d; }
#pragma unroll
  for (int m = 32; m; m >>= 1) s2 += __shfl_xor(s2, m);
  float rstd = rsqrtf(s2 * (1.f / HDIM) + 1e-5f);
  float acc[8];
#pragma unroll
  for (int e = 0; e < 8; ++e) acc[e] = 0.f;
#pragma unroll
  for (int j = 0; j < 16; ++j) {
    int h = j * 64 + lane;
    float hn = (v[j] - mu) * rstd * lnw[h] + lnb[h];
    hn = fminf(fmaxf(hn, -50.f), 50.f);
#pragma unroll
    for (int e = 0; e < 8; ++e) acc[e] += hn * rw[e * HDIM + h];
  }
#pragma unroll
  for (int e = 0; e < 8; ++e) {
    float a = acc[e];
#pragma unroll
    for (int m = 32; m; m >>= 1) a += __shfl_xor(a, m);
    acc[e] = a;
  }
  if (lane == 0) {
    float lg[8], mx = -1e30f;
#pragma unroll
    for (int e = 0; e < 8; ++e) {
      float l = fminf(fmaxf(acc[e], -10.f), 10.f);
      lg[e] = l;
      mx = fmaxf(mx, l);
    }
    float se = 0.f;
    float ex[8];
#pragma unroll
    for (int e = 0; e < 8; ++e) { ex[e] = expf(lg[e] - mx); se += ex[e]; }
    float inv = 1.f / se;
    float pr[8];
#pragma unroll
    for (int e = 0; e < 8; ++e) {
      float p = ex[e] * inv;
      pr[e] = fminf(fmaxf(p, 1e-4f), 1.f);
      probs_tok[t * 8 + e] = pr[e];
    }
    int i0 = 0; float v0 = pr[0];
#pragma unroll
    for (int e = 1; e < 8; ++e) if (pr[e] > v0) { v0 = pr[e]; i0 = e; }
    int i1 = -1; float v1 = -1.f;
#pragma unroll
    for (int e = 0; e < 8; ++e) if (e != i0 && pr[e] > v1) { v1 = pr[e]; i1 = e; }
    float dsum = fmaxf(v0 + v1, 1e-4f);
    top_i[2 * t] = i0; top_i[2 * t + 1] = i1;
    top_w[2 * t] = v0 / dsum; top_w[2 * t + 1] = v1 / dsum;
    float lse = mx + logf(se);
    zent[2 * t] = lse * lse;
    float ent = 0.f;
#pragma unroll
    for (int e = 0; e < 8; ++e) {
      float ps = fminf(fmaxf(pr[e], 1e-4f), 1.f - 1e-4f);
      ent -= ps * logf(ps);
    }
    zent[2 * t + 1] = ent;
  }
}

// ---------------- aux loss + 256-padded tile map (single block, deterministic) ----------------
__global__ __launch_bounds__(256) void aux_kernel(
    const int* __restrict__ top_i, const float* __restrict__ probs_tok,
    const float* __restrict__ zent, int* __restrict__ meta,
    int* __restrict__ ltok, float* __restrict__ lw,
    float* __restrict__ aux_out) {
  __shared__ int sc[8];
  __shared__ float red[256];
  __shared__ float sums[10];
  int tid = threadIdx.x;
  if (tid < 8) sc[tid] = 0;
  __syncthreads();
  for (int s = tid; s < 8192; s += 256) atomicAdd(&sc[top_i[s]], 1);
  // default-init padded token lists (scatter overwrites the live ones)
  for (int i = tid; i < ROWS_PAD; i += 256) { ltok[i] = 0; lw[i] = 0.f; }
  float pe[8] = {0, 0, 0, 0, 0, 0, 0, 0};
  float zs = 0.f, es = 0.f;
  for (int t = tid; t < 4096; t += 256) {
#pragma unroll
    for (int e = 0; e < 8; ++e) pe[e] += probs_tok[t * 8 + e];
    zs += zent[2 * t];
    es += zent[2 * t + 1];
  }
  for (int e = 0; e < 10; ++e) {
    float val = (e < 8) ? pe[e] : ((e == 8) ? zs : es);
    red[tid] = val;
    __syncthreads();
    for (int off = 128; off; off >>= 1) {
      if (tid < off) red[tid] += red[tid + off];
      __syncthreads();
    }
    if (tid == 0) sums[e] = red[0];
    __syncthreads();
  }
  if (tid == 0) {
    float lb = 0.f, usage = 0.f;
    for (int e = 0; e < 8; ++e) {
      float tpe = (float)sc[e] / 8192.f;
      float avg = sums[e] / 4096.f;
      lb += tpe * avg;
      usage += (tpe > 0.01f) ? 1.f : 0.f;
    }
    lb *= 8.f;
    float z_loss = (sums[8] / 4096.f) * 0.001f;
    float ent_loss = fmaxf(logf(8.f) - sums[9] / 4096.f, 0.f) * 0.01f;
    float util = (1.f - usage / 8.f) * 0.1f;
    float aux = fminf(fmaxf(lb + z_loss + ent_loss + util, 0.f), 10.f);
    *aux_out = aux;
    // 256-padded tile map
    int base = 0, tct = 0;
    for (int e = 0; e < 8; ++e) {
      int cnt = sc[e];
      meta[e] = cnt;
      meta[16 + e] = base;
      meta[32 + e] = 0;
      int nt = (cnt + 255) >> 8;
      for (int i = 0; i < nt; ++i) { meta[64 + tct] = e; meta[128 + tct] = base + i * 256; ++tct; }
      base += nt * 256;
    }
    meta[8] = TTOK;           // shared "expert"
    meta[16 + 8] = base;      // shared padded base
    meta[32 + 8] = 0;
    for (int i = 0; i < 16; ++i) { meta[64 + tct] = 8; meta[128 + tct] = base + i * 256; ++tct; }
    meta[48] = tct;
  }
}

// ---------------- scatter tokens into per-expert padded lists ----------------
__global__ __launch_bounds__(256) void scatter_kernel(
    const int* __restrict__ top_i, const float* __restrict__ top_w,
    int* __restrict__ meta, int* __restrict__ ltok, float* __restrict__ lw,
    int* __restrict__ rowslot) {
  int s = blockIdx.x * 256 + threadIdx.x;
  if (s < 8192) {
    int e = top_i[s];
    int pos = atomicAdd(&meta[32 + e], 1);
    int idx = meta[16 + e] + pos;
    ltok[idx] = s >> 1;
    lw[idx] = top_w[s];
    rowslot[s] = idx;
  }
  if (s < TTOK) {  // identity list for shared expert
    int sb = meta[16 + 8];
    ltok[sb + s] = s;
    lw[sb + s] = 1.f;
  }
}

// ---------------- GEMM1: P = clamp(silu(clamp(A*Wg^T)) * clamp(A*Wu^T)) ----------------
// BM=256, BN=128 (G and U), BK=64, 8 waves (2x4). Pipelined: issue all 8 stages
// for buf nxt at iter top, vmcnt(8) waits only the PREVIOUS iter's loads,
// 2 barriers/iter, no intra-iter barriers (reads hit cur, async writes hit nxt).
__global__ __launch_bounds__(512, 1) void gemm1_kernel(
    const unsigned short* __restrict__ hf,
    const unsigned short* __restrict__ wg_all,
    const unsigned short* __restrict__ wu_all,
    unsigned short* __restrict__ P,
    const int* __restrict__ meta, const int* __restrict__ ltok) {
  int mt = blockIdx.y, nt = blockIdx.x;
  if (mt >= meta[48]) return;
  int ex = meta[64 + mt];
  int r0 = meta[128 + mt];
  extern __shared__ unsigned short lds[];
  unsigned short* sA = lds;          // 2 x 16384 elems (256x64)
  unsigned short* sG = lds + 32768;  // 2 x 8192  (128x64)
  unsigned short* sU = lds + 49152;  // 2 x 8192
  int tid = threadIdx.x, lane = tid & 63, wv = tid >> 6;
  int wr = wv >> 2, wc = wv & 3;
  int l15 = lane & 15, l4 = lane >> 4;
  int srow = tid >> 3;              // staging row within a 64-row issue
  int gch = (tid & 7) ^ (srow & 7); // inverse-swizzled source 16B chunk
  int ldst = tid * 8;               // linear LDS dest elems within an issue
  const unsigned short* wg = wg_all + (size_t)ex * EXP_W_ELEMS;
  const unsigned short* wu = wu_all + (size_t)ex * EXP_W_ELEMS;
  int n0 = nt * 128;
  const unsigned short* srcA[4];
#pragma unroll
  for (int i = 0; i < 4; ++i) {
    int tok = ltok[r0 + i * 64 + srow];
    srcA[i] = hf + (size_t)tok * HDIM + gch * 8;
  }
  const unsigned short* srcG[2];
  const unsigned short* srcU[2];
#pragma unroll
  for (int i = 0; i < 2; ++i) {
    srcG[i] = wg + (size_t)(n0 + i * 64 + srow) * HDIM + gch * 8;
    srcU[i] = wu + (size_t)(n0 + i * 64 + srow) * HDIM + gch * 8;
  }
  // swizzled ds_read chunk per kk (row&7 == lane&7 for all frag rows)
  int ch0 = (0 + l4) ^ (lane & 7);
  int ch1 = (4 + l4) ^ (lane & 7);
  int baseA = (wr * 128 + l15) * 64;
  int baseG = (wc * 32 + l15) * 64;

  f32x4 zero = {0.f, 0.f, 0.f, 0.f};
  f32x4 accg[8][2], accu[8][2];
#pragma unroll
  for (int m = 0; m < 8; ++m)
#pragma unroll
    for (int n = 0; n < 2; ++n) { accg[m][n] = zero; accu[m][n] = zero; }

  // prologue: stage K-step 0 into buf0 (no wait here; t=0 top waits)
#pragma unroll
  for (int i = 0; i < 4; ++i) stage16(srcA[i], &sA[i * 4096 + ldst]);
#pragma unroll
  for (int i = 0; i < 2; ++i) stage16(srcG[i], &sG[i * 4096 + ldst]);
#pragma unroll
  for (int i = 0; i < 2; ++i) stage16(srcU[i], &sU[i * 4096 + ldst]);

  for (int t = 0; t < 16; ++t) {
    int cur = t & 1, nxt = cur ^ 1;
    int cbA = cur * 16384, cbG = cur * 8192;
    int nbA = nxt * 16384, nbG = nxt * 8192;
    if (t < 15) {
      int k1 = (t + 1) * 64;
      stage16(srcA[0] + k1, &sA[nbA + 0 * 4096 + ldst]);
      stage16(srcA[1] + k1, &sA[nbA + 1 * 4096 + ldst]);
      stage16(srcA[2] + k1, &sA[nbA + 2 * 4096 + ldst]);
      stage16(srcA[3] + k1, &sA[nbA + 3 * 4096 + ldst]);
      stage16(srcG[0] + k1, &sG[nbG + 0 * 4096 + ldst]);
      stage16(srcG[1] + k1, &sG[nbG + 1 * 4096 + ldst]);
      stage16(srcU[0] + k1, &sU[nbG + 0 * 4096 + ldst]);
      stage16(srcU[1] + k1, &sU[nbG + 1 * 4096 + ldst]);
      VM_WAIT(8);   // previous iter's 8 (buf cur) landed; these 8 stay in flight
    } else {
      VM_WAIT(0);
    }
    SBAR; FENCE;    // all waves' cur stages landed
    bf16x8 af0[8], af1[8], g0[2], g1[2], u0[2], u1[2];
    // ---- kk0 ----
#pragma unroll
    for (int m = 0; m < 8; ++m)
      af0[m] = *(const bf16x8*)&sA[cbA + baseA + m * 1024 + ch0 * 8];
#pragma unroll
    for (int n = 0; n < 2; ++n)
      g0[n] = *(const bf16x8*)&sG[cbG + baseG + n * 1024 + ch0 * 8];
    PRIO_HI;
#pragma unroll
    for (int m = 0; m < 8; ++m)
#pragma unroll
      for (int n = 0; n < 2; ++n)
        accg[m][n] = mfma16(af0[m], g0[n], accg[m][n]);
    PRIO_LO;
#pragma unroll
    for (int n = 0; n < 2; ++n)
      u0[n] = *(const bf16x8*)&sU[cbG + baseG + n * 1024 + ch0 * 8];
    PRIO_HI;
#pragma unroll
    for (int m = 0; m < 8; ++m)
#pragma unroll
      for (int n = 0; n < 2; ++n)
        accu[m][n] = mfma16(af0[m], u0[n], accu[m][n]);
    PRIO_LO;
    // ---- kk1 ----
#pragma unroll
    for (int m = 0; m < 8; ++m)
      af1[m] = *(const bf16x8*)&sA[cbA + baseA + m * 1024 + ch1 * 8];
#pragma unroll
    for (int n = 0; n < 2; ++n)
      g1[n] = *(const bf16x8*)&sG[cbG + baseG + n * 1024 + ch1 * 8];
    PRIO_HI;
#pragma unroll
    for (int m = 0; m < 8; ++m)
#pragma unroll
      for (int n = 0; n < 2; ++n)
        accg[m][n] = mfma16(af1[m], g1[n], accg[m][n]);
    PRIO_LO;
#pragma unroll
    for (int n = 0; n < 2; ++n)
      u1[n] = *(const bf16x8*)&sU[cbG + baseG + n * 1024 + ch1 * 8];
    PRIO_HI;
#pragma unroll
    for (int m = 0; m < 8; ++m)
#pragma unroll
      for (int n = 0; n < 2; ++n)
        accu[m][n] = mfma16(af1[m], u1[n], accu[m][n]);
    PRIO_LO;
    FENCE; SBAR;    // all waves done reading cur before t+1 overwrites it
  }
  // epilogue: SwiGLU, write bf16 P (padded rows junk, never read)
  int rbase = r0 + wr * 128 + l4 * 4;
  int cbase = n0 + wc * 32 + l15;
#pragma unroll
  for (int m = 0; m < 8; ++m) {
#pragma unroll
    for (int r = 0; r < 4; ++r) {
      size_t prow = (size_t)(rbase + m * 16 + r) * IDIM;
#pragma unroll
      for (int n = 0; n < 2; ++n) {
        float g = clamp500(accg[m][n][r]);
        float u = clamp500(accu[m][n][r]);
        float sl = g / (1.f + __expf(-g));
        float p = clamp500(sl * u);
        P[prow + cbase + n * 16] = f2bf(p);
      }
    }
  }
}

// ---------------- GEMM2: slot = weight * clamp(P*Wd^T)  (shared: clamp(clamp(.)*sig)) ----------------
// BM=256, BN=256, BK=64, 8 waves (2x4), same pipelined schedule as gemm1.
__global__ __launch_bounds__(512, 1) void gemm2_kernel(
    const unsigned short* __restrict__ P,
    const unsigned short* __restrict__ wd_all,
    unsigned short* __restrict__ slot,
    const int* __restrict__ meta, const float* __restrict__ lw,
    const float* __restrict__ sgate) {
  int mt = blockIdx.y, nt = blockIdx.x;
  if (mt >= meta[48]) return;
  int ex = meta[64 + mt];
  int r0 = meta[128 + mt];
  extern __shared__ unsigned short lds[];
  unsigned short* sA = lds;          // 2 x 16384 (256x64)
  unsigned short* sB = lds + 32768;  // 2 x 16384 (256x64)
  int tid = threadIdx.x, lane = tid & 63, wv = tid >> 6;
  int wr = wv >> 2, wc = wv & 3;
  int l15 = lane & 15, l4 = lane >> 4;
  int srow = tid >> 3;
  int gch = (tid & 7) ^ (srow & 7);
  int ldst = tid * 8;
  const unsigned short* wd = wd_all + (size_t)ex * EXP_W_ELEMS;
  int n0 = nt * 256;
  const unsigned short* srcA[4];
  const unsigned short* srcB[4];
#pragma unroll
  for (int i = 0; i < 4; ++i) {
    srcA[i] = P + (size_t)(r0 + i * 64 + srow) * IDIM + gch * 8;
    srcB[i] = wd + (size_t)(n0 + i * 64 + srow) * IDIM + gch * 8;
  }
  int ch0 = (0 + l4) ^ (lane & 7);
  int ch1 = (4 + l4) ^ (lane & 7);
  int baseA = (wr * 128 + l15) * 64;
  int baseB = (wc * 64 + l15) * 64;

  f32x4 zero = {0.f, 0.f, 0.f, 0.f};
  f32x4 acc[8][4];
#pragma unroll
  for (int m = 0; m < 8; ++m)
#pragma unroll
    for (int n = 0; n < 4; ++n) acc[m][n] = zero;

  // prologue
#pragma unroll
  for (int i = 0; i < 4; ++i) stage16(srcA[i], &sA[i * 4096 + ldst]);
#pragma unroll
  for (int i = 0; i < 4; ++i) stage16(srcB[i], &sB[i * 4096 + ldst]);

  for (int t = 0; t < 32; ++t) {
    int cur = t & 1, nxt = cur ^ 1;
    int cb = cur * 16384, nb = nxt * 16384;
    if (t < 31) {
      int k1 = (t + 1) * 64;
      stage16(srcA[0] + k1, &sA[nb + 0 * 4096 + ldst]);
      stage16(srcA[1] + k1, &sA[nb + 1 * 4096 + ldst]);
      stage16(srcA[2] + k1, &sA[nb + 2 * 4096 + ldst]);
      stage16(srcA[3] + k1, &sA[nb + 3 * 4096 + ldst]);
      stage16(srcB[0] + k1, &sB[nb + 0 * 4096 + ldst]);
      stage16(srcB[1] + k1, &sB[nb + 1 * 4096 + ldst]);
      stage16(srcB[2] + k1, &sB[nb + 2 * 4096 + ldst]);
      stage16(srcB[3] + k1, &sB[nb + 3 * 4096 + ldst]);
      VM_WAIT(8);
    } else {
      VM_WAIT(0);
    }
    SBAR; FENCE;
    bf16x8 af0[8], af1[8], b0[4], b1[4];
    // ---- kk0 ----
#pragma unroll
    for (int m = 0; m < 8; ++m)
      af0[m] = *(const bf16x8*)&sA[cb + baseA + m * 1024 + ch0 * 8];
#pragma unroll
    for (int n = 0; n < 4; ++n)
      b0[n] = *(const bf16x8*)&sB[cb + baseB + n * 1024 + ch0 * 8];
    PRIO_HI;
#pragma unroll
    for (int m = 0; m < 8; ++m)
#pragma unroll
      for (int n = 0; n < 4; ++n)
        acc[m][n] = mfma16(af0[m], b0[n], acc[m][n]);
    PRIO_LO;
    // ---- kk1 ----
#pragma unroll
    for (int m = 0; m < 8; ++m)
      af1[m] = *(const bf16x8*)&sA[cb + baseA + m * 1024 + ch1 * 8];
#pragma unroll
    for (int n = 0; n < 4; ++n)
      b1[n] = *(const bf16x8*)&sB[cb + baseB + n * 1024 + ch1 * 8];
    PRIO_HI;
#pragma unroll
    for (int m = 0; m < 8; ++m)
#pragma unroll
      for (int n = 0; n < 4; ++n)
        acc[m][n] = mfma16(af1[m], b1[n], acc[m][n]);
    PRIO_LO;
    FENCE; SBAR;
  }
  float gsig = 1.f / (1.f + __expf(-sgate[0]));
  int rbase = r0 + wr * 128 + l4 * 4;
  int cbase = n0 + wc * 64 + l15;
#pragma unroll
  for (int m = 0; m < 8; ++m) {
#pragma unroll
    for (int r = 0; r < 4; ++r) {
      int row = rbase + m * 16 + r;
      float wgt = (ex == 8) ? 1.f : lw[row];
      size_t srow_o = (size_t)row * HDIM;
#pragma unroll
      for (int n = 0; n < 4; ++n) {
        float o = clamp500(acc[m][n][r]);
        float val = (ex == 8) ? clamp500(o * gsig) : wgt * o;
        slot[srow_o + cbase + n * 16] = f2bf(val);
      }
    }
  }
}

// ---------------- combine: final = clamp(slot0 + slot1 + shared) ----------------
__global__ __launch_bounds__(256) void combine_kernel(
    const unsigned short* __restrict__ slot, const int* __restrict__ rowslot,
    const int* __restrict__ meta, float* __restrict__ out) {
  int i = blockIdx.x * 256 + threadIdx.x;  // 4-elem group index
  int t = i >> 8;
  int c = (i & 255) * 4;
  int sb = meta[16 + 8];
  int r0 = rowslot[2 * t], r1 = rowslot[2 * t + 1];
  ushort4 va = *(const ushort4*)(slot + (size_t)r0 * HDIM + c);
  ushort4 vb = *(const ushort4*)(slot + (size_t)r1 * HDIM + c);
  ushort4 vs = *(const ushort4*)(slot + (size_t)(sb + t) * HDIM + c);
  float4 o;
  o.x = clamp500(bf2f(va.x) + bf2f(vb.x) + bf2f(vs.x));
  o.y = clamp500(bf2f(va.y) + bf2f(vb.y) + bf2f(vs.y));
  o.z = clamp500(bf2f(va.z) + bf2f(vb.z) + bf2f(vs.z));
  o.w = clamp500(bf2f(va.w) + bf2f(vb.w) + bf2f(vs.w));
  *(float4*)(out + (size_t)t * HDIM + c) = o;
}

// ---------------- launch ----------------
extern "C" void kernel_launch(void* const* d_in, const int* in_sizes, int n_in,
                              void* d_out, int out_size, void* d_ws, size_t ws_size,
                              hipStream_t stream) {
  const float* x     = (const float*)d_in[0];
  const float* lnw   = (const float*)d_in[1];
  const float* lnb   = (const float*)d_in[2];
  const float* rw    = (const float*)d_in[3];
  const float* wg_f  = (const float*)d_in[4];
  const float* wu_f  = (const float*)d_in[5];
  const float* wd_f  = (const float*)d_in[6];
  const float* swg_f = (const float*)d_in[7];
  const float* swu_f = (const float*)d_in[8];
  const float* swd_f = (const float*)d_in[9];
  const float* sgate = (const float*)d_in[10];
  float* out = (float*)d_out;

  char* ws = (char*)d_ws;
  unsigned short* wgb = (unsigned short*)(ws + OFF_WG);
  unsigned short* wub = (unsigned short*)(ws + OFF_WU);
  unsigned short* wdb = (unsigned short*)(ws + OFF_WD);
  unsigned short* hf  = (unsigned short*)(ws + OFF_HF);
  unsigned short* P   = (unsigned short*)(ws + OFF_P);
  unsigned short* slot = (unsigned short*)(ws + OFF_SLOT);
  int*   top_i   = (int*)(ws + OFF_TOPI);
  float* top_w   = (float*)(ws + OFF_TOPW);
  float* probs   = (float*)(ws + OFF_PROB);
  float* zent    = (float*)(ws + OFF_ZENT);
  int*   meta    = (int*)(ws + OFF_META);
  int*   ltok    = (int*)(ws + OFF_LTOK);
  float* lw      = (float*)(ws + OFF_LW);
  int*   rowslot = (int*)(ws + OFF_ROWS);

  hipFuncSetAttribute((const void*)gemm1_kernel,
                      hipFuncAttributeMaxDynamicSharedMemorySize, 131072);
  hipFuncSetAttribute((const void*)gemm2_kernel,
                      hipFuncAttributeMaxDynamicSharedMemorySize, 131072);

  // weights fp32 -> bf16 (experts 0..7 from dense arrays, shared as expert 8)
  cvt_kernel<<<2048, 256, 0, stream>>>(wg_f, wgb, (int)(8 * EXP_W_ELEMS / 4));
  cvt_kernel<<<2048, 256, 0, stream>>>(wu_f, wub, (int)(8 * EXP_W_ELEMS / 4));
  cvt_kernel<<<2048, 256, 0, stream>>>(wd_f, wdb, (int)(8 * EXP_W_ELEMS / 4));
  cvt_kernel<<<512, 256, 0, stream>>>(swg_f, wgb + 8 * EXP_W_ELEMS, (int)(EXP_W_ELEMS / 4));
  cvt_kernel<<<512, 256, 0, stream>>>(swu_f, wub + 8 * EXP_W_ELEMS, (int)(EXP_W_ELEMS / 4));
  cvt_kernel<<<512, 256, 0, stream>>>(swd_f, wdb + 8 * EXP_W_ELEMS, (int)(EXP_W_ELEMS / 4));

  router_kernel<<<TTOK / 4, 256, 0, stream>>>(x, lnw, lnb, rw, hf, top_i, top_w, probs, zent);
  aux_kernel<<<1, 256, 0, stream>>>(top_i, probs, zent, meta, ltok, lw, out + (size_t)TTOK * HDIM);
  scatter_kernel<<<32, 256, 0, stream>>>(top_i, top_w, meta, ltok, lw, rowslot);

  gemm1_kernel<<<dim3(16, MT_MAX), 512, 131072, stream>>>(hf, wgb, wub, P, meta, ltok);
  gemm2_kernel<<<dim3(4, MT_MAX), 512, 131072, stream>>>(P, wdb, slot, meta, lw, sgate);
  combine_kernel<<<TTOK * HDIM / 4 / 256, 256, 0, stream>>>(slot, rowslot, meta, out);
}